// Round 5
// baseline (103.062 us; speedup 1.0000x reference)
//
#include <hip/hip_runtime.h>
#include <math.h>

#define IOU_TH 0.5f
#define EPSF 1e-6f
#define GPER 8
#define ASPLIT 16
#define NBIN 4096

__device__ __forceinline__ float sl1(float x) {
    float ax = fabsf(x);
    return ax < 1.f ? 0.5f * x * x : ax - 0.5f;
}

// ---------------- kernel 2: best anchor per (b,g), A split 16-way, merged via atomicMax ----
__global__ __launch_bounds__(256) void kBestAnchor(
    const float4* __restrict__ anchors, const float4* __restrict__ gt,
    unsigned long long* __restrict__ wsKey, int A, int G)
{
    int nch = G / GPER;
    int b   = blockIdx.x / (nch * ASPLIT);
    int r   = blockIdx.x % (nch * ASPLIT);
    int g0  = (r / ASPLIT) * GPER;
    int aChunk = A / ASPLIT;
    int a0  = (r % ASPLIT) * aChunk;

    float4 gb[GPER]; float ga[GPER];
#pragma unroll
    for (int j = 0; j < GPER; ++j) {
        gb[j] = gt[(size_t)b * G + g0 + j];
        ga[j] = (gb[j].z - gb[j].x) * (gb[j].w - gb[j].y);
    }
    float bi[GPER], bd[GPER]; int bx[GPER];
#pragma unroll
    for (int j = 0; j < GPER; ++j) { bi[j] = -1.f; bd[j] = 1.f; bx[j] = a0; }
    for (int a = a0 + threadIdx.x; a < a0 + aChunk; a += 256) {
        float4 ab = anchors[a];
        float aa = (ab.z - ab.x) * (ab.w - ab.y);
#pragma unroll
        for (int j = 0; j < GPER; ++j) {
            float wx = fmaxf(fminf(ab.z, gb[j].z) - fmaxf(ab.x, gb[j].x), 0.f);
            float wy = fmaxf(fminf(ab.w, gb[j].w) - fmaxf(ab.y, gb[j].y), 0.f);
            float inter = wx * wy;
            float den = aa + ga[j] - inter + EPSF;
            if (inter * bd[j] > bi[j] * den) { bi[j] = inter; bd[j] = den; bx[j] = a; }
        }
    }
    int lane = threadIdx.x & 63, wv = threadIdx.x >> 6;
    __shared__ float ri[4][GPER], rd[4][GPER]; __shared__ int rx[4][GPER];
#pragma unroll
    for (int j = 0; j < GPER; ++j) {
        float ci = bi[j], cd = bd[j]; int cx = bx[j];
        for (int off = 32; off > 0; off >>= 1) {
            float oi = __shfl_down(ci, off);
            float od = __shfl_down(cd, off);
            int   ox = __shfl_down(cx, off);
            if (lane + off < 64) {
                float lp = oi * cd, rp = ci * od;
                if (lp > rp || (lp == rp && ox < cx)) { ci = oi; cd = od; cx = ox; }
            }
        }
        if (lane == 0) { ri[wv][j] = ci; rd[wv][j] = cd; rx[wv][j] = cx; }
    }
    __syncthreads();
    if (threadIdx.x < GPER) {
        int j = threadIdx.x;
        float ci = ri[0][j], cd = rd[0][j]; int cx = rx[0][j];
        for (int w = 1; w < 4; ++w) {
            float oi = ri[w][j], od = rd[w][j]; int ox = rx[w][j];
            float lp = oi * cd, rp = ci * od;
            if (lp > rp || (lp == rp && ox < cx)) { ci = oi; cd = od; cx = ox; }
        }
        float iou = ci / cd;
        unsigned long long key =
            ((unsigned long long)__float_as_uint(iou) << 32) | (unsigned int)(~(unsigned int)cx);
        atomicMax(&wsKey[(size_t)b * G + g0 + j], key);
    }
}

// ---------------- kernel 2b: decode winners -> flag; precompute gt areas ----------------
__global__ void kForce(const unsigned long long* __restrict__ wsKey,
                       const float4* __restrict__ gt,
                       unsigned char* __restrict__ flag, float* __restrict__ gtArea,
                       int A, int G, int BG)
{
    int i = blockIdx.x * 256 + threadIdx.x;
    if (i < BG) {
        unsigned long long k = wsKey[i];
        unsigned int idx = ~(unsigned int)(k & 0xFFFFFFFFull);
        int b = i / G;
        flag[(size_t)b * A + idx] = 1;
        float4 g4 = gt[i];
        gtArea[i] = (g4.z - g4.x) * (g4.w - g4.y);
    }
}

// ---------------- kernel 3: per-anchor match + losses + LDS neg-histogram ----------------
__global__ __launch_bounds__(256) void kMain(
    const float4* __restrict__ bbox, const float* __restrict__ conf,
    const float4* __restrict__ anchors, const float4* __restrict__ gt,
    const float* __restrict__ gtArea,
    const unsigned char* __restrict__ forcedFlag,
    float* __restrict__ neg, int* __restrict__ histC,
    float* __restrict__ accLoc, float* __restrict__ accFpos,
    float* __restrict__ accSiou, int* __restrict__ accNpos,
    int A, int G)
{
    __shared__ float4 sGt[64];                 // only for the divergent matched-box gather
    __shared__ int sHist[NBIN];
    __shared__ float red[4][3]; __shared__ int redN[4];
    int b = blockIdx.y;
    for (int i = threadIdx.x; i < NBIN; i += 256) sHist[i] = 0;
    if (threadIdx.x < G) sGt[threadIdx.x] = gt[(size_t)b * G + threadIdx.x];

    int a = blockIdx.x * 256 + threadIdx.x;    // A % 256 == 0
    // hoisted global loads (issue early, consume late)
    float4 an = anchors[a];
    float4 p4 = bbox[(size_t)b * A + a];
    float  cp = conf[(size_t)b * A + a];
    unsigned char ff = forcedFlag[(size_t)b * A + a];
    float aa = (an.z - an.x) * (an.w - an.y);

    // wave-uniform gt stream -> scalar loads (s_load_dwordx4 / s_load_dword)
    const float4* __restrict__ gtb = gt + (size_t)b * G;
    const float*  __restrict__ gab = gtArea + (size_t)b * G;

    float bi[4], bd[4]; int bx[4];
#pragma unroll
    for (int c = 0; c < 4; ++c) { bi[c] = -1.f; bd[c] = 1.f; bx[c] = c; }
#pragma unroll 2
    for (int g = 0; g < G; g += 4) {
        float4 q0 = gtb[g + 0]; float g0 = gab[g + 0];
        float4 q1 = gtb[g + 1]; float g1 = gab[g + 1];
        float4 q2 = gtb[g + 2]; float g2 = gab[g + 2];
        float4 q3 = gtb[g + 3]; float g3 = gab[g + 3];
        {
            float wx = fmaxf(fminf(an.z, q0.z) - fmaxf(an.x, q0.x), 0.f);
            float wy = fmaxf(fminf(an.w, q0.w) - fmaxf(an.y, q0.y), 0.f);
            float inter = wx * wy;
            float den = aa + g0 - inter + EPSF;
            if (inter * bd[0] > bi[0] * den) { bi[0] = inter; bd[0] = den; bx[0] = g; }
        }
        {
            float wx = fmaxf(fminf(an.z, q1.z) - fmaxf(an.x, q1.x), 0.f);
            float wy = fmaxf(fminf(an.w, q1.w) - fmaxf(an.y, q1.y), 0.f);
            float inter = wx * wy;
            float den = aa + g1 - inter + EPSF;
            if (inter * bd[1] > bi[1] * den) { bi[1] = inter; bd[1] = den; bx[1] = g + 1; }
        }
        {
            float wx = fmaxf(fminf(an.z, q2.z) - fmaxf(an.x, q2.x), 0.f);
            float wy = fmaxf(fminf(an.w, q2.w) - fmaxf(an.y, q2.y), 0.f);
            float inter = wx * wy;
            float den = aa + g2 - inter + EPSF;
            if (inter * bd[2] > bi[2] * den) { bi[2] = inter; bd[2] = den; bx[2] = g + 2; }
        }
        {
            float wx = fmaxf(fminf(an.z, q3.z) - fmaxf(an.x, q3.x), 0.f);
            float wy = fmaxf(fminf(an.w, q3.w) - fmaxf(an.y, q3.y), 0.f);
            float inter = wx * wy;
            float den = aa + g3 - inter + EPSF;
            if (inter * bd[3] > bi[3] * den) { bi[3] = inter; bd[3] = den; bx[3] = g + 3; }
        }
    }
    float Bi = bi[0], Bd = bd[0]; int Bx = bx[0];
#pragma unroll
    for (int c = 1; c < 4; ++c) {
        float lp = bi[c] * Bd, rp = Bi * bd[c];
        if (lp > rp || (lp == rp && bx[c] < Bx)) { Bi = bi[c]; Bd = bd[c]; Bx = bx[c]; }
    }
    float best_iou = Bi / Bd;
    bool pos = (best_iou > IOU_TH) || (ff != 0);

    __syncthreads();   // sGt staged (needed below); also hist zeroed before atomics

    float box_loss = 0.f, a_iou = 0.f;
    bool anyPos = __any(pos);
    if (anyPos) {      // wave-uniform: skipped entirely by all-negative waves (~95%)
        float4 m = sGt[Bx];
        float pa = (p4.z - p4.x) * (p4.w - p4.y);
        float ta = (m.z - m.x) * (m.w - m.y);
        float wx = fmaxf(fminf(p4.z, m.z) - fmaxf(p4.x, m.x), 0.f);
        float wy = fmaxf(fminf(p4.w, m.w) - fmaxf(p4.y, m.y), 0.f);
        float inter = wx * wy;
        a_iou = inter / (pa + ta - inter + EPSF);
        float ex = fmaxf(fmaxf(p4.z, m.z) - fminf(p4.x, m.x), 0.f);
        float ey = fmaxf(fmaxf(p4.w, m.w) - fminf(p4.y, m.y), 0.f);
        float enc = ex * ey + EPSF;
        float uni = pa + ta - a_iou * pa * ta;
        float gl = 1.f - (a_iou - (enc - uni) / enc);
        float cl = sl1((p4.x + p4.z) * 0.5f - (m.x + m.z) * 0.5f)
                 + sl1((p4.y + p4.w) * 0.5f - (m.y + m.w) * 0.5f);
        float szl = sl1((p4.z - p4.x) - (m.z - m.x)) + sl1((p4.w - p4.y) - (m.w - m.y));
        box_loss = 0.5f * (cl + szl) + 0.5f * gl;
    }
    float t = pos ? a_iou : 0.f;
    float pcl = fminf(fmaxf(cp, 1e-7f), 1.f - 1e-7f);
    float bce;
    if (anyPos) bce = -(t * logf(pcl) + (1.f - t) * log1pf(-pcl));
    else        bce = -log1pf(-pcl);            // t == 0 exactly
    float pt = (t > 0.f) ? cp : (1.f - cp);
    float om = 1.f - pt;
    float f = om * om * ((t > 0.f) ? 0.25f : 0.75f) * bce;

    neg[(size_t)b * A + a] = pos ? 0.f : f;
    if (!pos) {
        unsigned int u = __float_as_uint(f);
        atomicAdd(&sHist[u >> 19], 1);
    }
    float vloc = pos ? box_loss : 0.f;
    float vf = pos ? f : 0.f;
    float vs = pos ? a_iou : 0.f;
    int vn = pos ? 1 : 0;
    int lane = threadIdx.x & 63, wv = threadIdx.x >> 6;
    for (int off = 32; off > 0; off >>= 1) {
        vloc += __shfl_down(vloc, off);
        vf   += __shfl_down(vf, off);
        vs   += __shfl_down(vs, off);
        vn   += __shfl_down(vn, off);
    }
    if (lane == 0) { red[wv][0] = vloc; red[wv][1] = vf; red[wv][2] = vs; redN[wv] = vn; }
    __syncthreads();   // orders sHist atomics before flush + red[] before sum
    if (threadIdx.x == 0) {
        float sl = 0.f, sf = 0.f, ss = 0.f; int sn = 0;
#pragma unroll
        for (int w = 0; w < 4; ++w) { sl += red[w][0]; sf += red[w][1]; ss += red[w][2]; sn += redN[w]; }
        atomicAdd(&accLoc[b], sl);
        atomicAdd(&accFpos[b], sf);
        atomicAdd(&accSiou[b], ss);
        atomicAdd(&accNpos[b], sn);
    }
    int* hb = histC + (size_t)b * NBIN;
    for (int i = threadIdx.x; i < NBIN; i += 256) {
        int c = sHist[i];
        if (c) atomicAdd(&hb[i], c);
    }
}

// ---------------- kernel 4: top-k sum = hist suffix-scan + one A pass + candidate radix ----
__global__ __launch_bounds__(1024) void kSelect2(
    const float* __restrict__ neg, const int* __restrict__ histC,
    const int* __restrict__ accNpos, const float* __restrict__ accFpos,
    float* __restrict__ cand, float* __restrict__ accConf, int A)
{
    __shared__ int scanI[1024];
    __shared__ float scanF[1024];
    __shared__ int cnt[1024];
    __shared__ float sm[1024];
    __shared__ float redF[16];
    __shared__ int sh_cb, sh_rem, sh_n, sh_done;
    __shared__ float sh_res, sh_sumHigh;

    int b = blockIdx.x;
    int t = threadIdx.x;
    int npos = accNpos[b];
    int k = min(npos * 3, A - npos);
    if (k <= 0) { if (t == 0) accConf[b] = accFpos[b]; return; }

    int4 c4 = ((const int4*)(histC + (size_t)b * NBIN))[t];
    scanI[t] = c4.x + c4.y + c4.z + c4.w;
    __syncthreads();
    for (int off = 1; off < 1024; off <<= 1) {
        int v = (t + off < 1024) ? scanI[t + off] : 0;
        __syncthreads();
        scanI[t] += v;
        __syncthreads();
    }
    {
        int above = (t + 1 < 1024) ? scanI[t + 1] : 0;
        if (above < k && scanI[t] >= k) {
            int carr[4] = {c4.x, c4.y, c4.z, c4.w};
            int cum = above;
            for (int j = 3; j >= 0; --j) {
                cum += carr[j];
                if (cum >= k) { sh_cb = 4 * t + j; sh_rem = k - (cum - carr[j]); break; }
            }
            sh_n = 0; sh_res = 0.f; sh_done = 0;
        }
    }
    __syncthreads();
    int cb = sh_cb;

    float localSum = 0.f;
    const float4* nb4 = (const float4*)(neg + (size_t)b * A);
    float* cb_buf = cand + (size_t)b * A;
    for (int i = t; i < A / 4; i += 1024) {
        float4 v = nb4[i];
        float vv[4] = {v.x, v.y, v.z, v.w};
#pragma unroll
        for (int j = 0; j < 4; ++j) {
            int bin = (int)(__float_as_uint(vv[j]) >> 19);
            if (bin > cb) localSum += vv[j];
            else if (bin == cb) {
                int idx = atomicAdd(&sh_n, 1);
                cb_buf[idx] = vv[j];
            }
        }
    }
    {
        int lane = t & 63, wv = t >> 6;
        for (int off = 32; off > 0; off >>= 1) localSum += __shfl_down(localSum, off);
        if (lane == 0) redF[wv] = localSum;
    }
    __syncthreads();
    if (t == 0) {
        float tot = 0.f;
        for (int w = 0; w < 16; ++w) tot += redF[w];
        sh_sumHigh = tot;
    }
    __syncthreads();
    int n = sh_n;
    int rem = sh_rem;

    cnt[t] = 0; sm[t] = 0.f;
    __syncthreads();
    for (int i = t; i < n; i += 1024) {
        float v = cb_buf[i];
        int bin = (int)((__float_as_uint(v) >> 9) & 1023u);
        atomicAdd(&cnt[bin], 1);
        atomicAdd(&sm[bin], v);
    }
    __syncthreads();
    scanI[t] = cnt[t]; scanF[t] = sm[t];
    __syncthreads();
    for (int off = 1; off < 1024; off <<= 1) {
        int vi = 0; float vf = 0.f;
        if (t + off < 1024) { vi = scanI[t + off]; vf = scanF[t + off]; }
        __syncthreads();
        scanI[t] += vi; scanF[t] += vf;
        __syncthreads();
    }
    {
        int aboveC = (t + 1 < 1024) ? scanI[t + 1] : 0;
        if (aboveC < rem && scanI[t] >= rem) {
            float aboveS = (t + 1 < 1024) ? scanF[t + 1] : 0.f;
            int need = rem - aboveC;
            if (cnt[t] == need) { sh_res += aboveS + sm[t]; sh_done = 1; }
            else { sh_res += aboveS; sh_rem = need; sh_cb = t; }
        }
    }
    __syncthreads();
    if (!sh_done) {
        int cb2 = sh_cb;
        rem = sh_rem;
        if (t < 512) { cnt[t] = 0; sm[t] = 0.f; }
        __syncthreads();
        for (int i = t; i < n; i += 1024) {
            float v = cb_buf[i];
            unsigned int u = __float_as_uint(v);
            if ((int)((u >> 9) & 1023u) == cb2) {
                int bin = (int)(u & 511u);
                atomicAdd(&cnt[bin], 1);
                atomicAdd(&sm[bin], v);
            }
        }
        __syncthreads();
        scanI[t] = (t < 512) ? cnt[t] : 0;
        scanF[t] = (t < 512) ? sm[t] : 0.f;
        __syncthreads();
        for (int off = 1; off < 512; off <<= 1) {
            int vi = 0; float vf = 0.f;
            if (t + off < 512) { vi = scanI[t + off]; vf = scanF[t + off]; }
            __syncthreads();
            if (t < 512) { scanI[t] += vi; scanF[t] += vf; }
            __syncthreads();
        }
        if (t < 512) {
            int aboveC = (t + 1 < 512) ? scanI[t + 1] : 0;
            if (aboveC < rem && scanI[t] >= rem) {
                float aboveS = (t + 1 < 512) ? scanF[t + 1] : 0.f;
                int need = rem - aboveC;
                if (cnt[t] == need) {
                    sh_res += aboveS + sm[t];
                } else {
                    unsigned int u = ((unsigned int)cb << 19) | ((unsigned int)cb2 << 9) | (unsigned int)t;
                    sh_res += aboveS + (float)need * __uint_as_float(u);
                }
            }
        }
        __syncthreads();
    }
    if (t == 0) accConf[b] = sh_sumHigh + sh_res + accFpos[b];
}

// ---------------- kernel 5: final reduce ----------------
__global__ void kFinal(const float* __restrict__ accLoc, const float* __restrict__ accConf,
                       const float* __restrict__ accSiou, const int* __restrict__ accNpos,
                       float* __restrict__ out, int B)
{
    int lane = threadIdx.x;
    float loc = 0.f, cf = 0.f, si = 0.f; int np = 0;
    if (lane < B) { loc = accLoc[lane]; cf = accConf[lane]; si = accSiou[lane]; np = accNpos[lane]; }
    for (int off = 32; off > 0; off >>= 1) {
        loc += __shfl_down(loc, off);
        cf  += __shfl_down(cf, off);
        si  += __shfl_down(si, off);
        np  += __shfl_down(np, off);
    }
    if (lane == 0) {
        float denom = fmaxf(1.f, (float)np);
        float tl = loc / denom, tc = cf / denom;
        out[0] = tl + tc;
        out[1] = tc;
        out[2] = tl;
        out[3] = si / denom;
    }
}

extern "C" void kernel_launch(void* const* d_in, const int* in_sizes, int n_in,
                              void* d_out, int out_size, void* d_ws, size_t ws_size,
                              hipStream_t stream)
{
    const float4* bbox    = (const float4*)d_in[0];
    const float*  conf    = (const float*)d_in[1];
    const float4* anchors = (const float4*)d_in[2];
    const float4* gt      = (const float4*)d_in[3];
    int A = in_sizes[2] / 4;
    int B = in_sizes[1] / A;
    int G = in_sizes[3] / (4 * B);
    float* out = (float*)d_out;

    char* ws = (char*)d_ws;
    size_t off = 0;
    float* neg    = (float*)(ws + off); off += (size_t)B * A * sizeof(float);
    float* cand   = (float*)(ws + off); off += (size_t)B * A * sizeof(float);
    float* gtArea = (float*)(ws + off); off += (size_t)B * G * sizeof(float);
    size_t zOff = off;
    unsigned char* forcedFlag = (unsigned char*)(ws + off); off += (size_t)B * A;
    unsigned long long* wsKey = (unsigned long long*)(ws + off); off += (size_t)B * G * 8;
    int* histC = (int*)(ws + off); off += (size_t)B * NBIN * sizeof(int);
    float* accLoc  = (float*)(ws + off); off += (size_t)B * sizeof(float);
    float* accFpos = (float*)(ws + off); off += (size_t)B * sizeof(float);
    float* accSiou = (float*)(ws + off); off += (size_t)B * sizeof(float);
    float* accConf = (float*)(ws + off); off += (size_t)B * sizeof(float);
    int*   accNpos = (int*)(ws + off);   off += (size_t)B * sizeof(int);
    size_t zBytes = off - zOff;

    hipMemsetAsync(ws + zOff, 0, zBytes, stream);

    int nch = G / GPER;
    kBestAnchor<<<dim3(B * nch * ASPLIT), 256, 0, stream>>>(anchors, gt, wsKey, A, G);
    int BG = B * G;
    kForce<<<dim3((BG + 255) / 256), 256, 0, stream>>>(wsKey, gt, forcedFlag, gtArea, A, G, BG);
    kMain<<<dim3(A / 256, B), 256, 0, stream>>>(bbox, conf, anchors, gt, gtArea, forcedFlag,
                                                neg, histC, accLoc, accFpos, accSiou, accNpos, A, G);
    kSelect2<<<dim3(B), 1024, 0, stream>>>(neg, histC, accNpos, accFpos, cand, accConf, A);
    kFinal<<<1, 64, 0, stream>>>(accLoc, accConf, accSiou, accNpos, out, B);
}

// Round 6
// 79.665 us; speedup vs baseline: 1.2937x; 1.2937x over previous
//
#include <hip/hip_runtime.h>
#include <math.h>

#define IOU_TH 0.5f
#define EPSF 1e-6f
#define GPER 8
#define ASPLIT 16
#define NBIN 4096

__device__ __forceinline__ float sl1(float x) {
    float ax = fabsf(x);
    return ax < 1.f ? 0.5f * x * x : ax - 0.5f;
}

// ---------------- kernel 2: best anchor per (b,g), A split 16-way, merged via atomicMax ----
__global__ __launch_bounds__(256) void kBestAnchor(
    const float4* __restrict__ anchors, const float4* __restrict__ gt,
    unsigned long long* __restrict__ wsKey, int A, int G)
{
    int nch = G / GPER;
    int b   = blockIdx.x / (nch * ASPLIT);
    int r   = blockIdx.x % (nch * ASPLIT);
    int g0  = (r / ASPLIT) * GPER;
    int aChunk = A / ASPLIT;
    int a0  = (r % ASPLIT) * aChunk;

    float4 gb[GPER]; float ga[GPER];
#pragma unroll
    for (int j = 0; j < GPER; ++j) {
        gb[j] = gt[(size_t)b * G + g0 + j];
        ga[j] = (gb[j].z - gb[j].x) * (gb[j].w - gb[j].y);
    }
    float bi[GPER], bd[GPER]; int bx[GPER];
#pragma unroll
    for (int j = 0; j < GPER; ++j) { bi[j] = -1.f; bd[j] = 1.f; bx[j] = a0; }
    for (int a = a0 + threadIdx.x; a < a0 + aChunk; a += 256) {
        float4 ab = anchors[a];
        float aa = (ab.z - ab.x) * (ab.w - ab.y);
#pragma unroll
        for (int j = 0; j < GPER; ++j) {
            float wx = fmaxf(fminf(ab.z, gb[j].z) - fmaxf(ab.x, gb[j].x), 0.f);
            float wy = fmaxf(fminf(ab.w, gb[j].w) - fmaxf(ab.y, gb[j].y), 0.f);
            float inter = wx * wy;
            float den = aa + ga[j] - inter + EPSF;
            if (inter * bd[j] > bi[j] * den) { bi[j] = inter; bd[j] = den; bx[j] = a; }
        }
    }
    int lane = threadIdx.x & 63, wv = threadIdx.x >> 6;
    __shared__ float ri[4][GPER], rd[4][GPER]; __shared__ int rx[4][GPER];
#pragma unroll
    for (int j = 0; j < GPER; ++j) {
        float ci = bi[j], cd = bd[j]; int cx = bx[j];
        for (int off = 32; off > 0; off >>= 1) {
            float oi = __shfl_down(ci, off);
            float od = __shfl_down(cd, off);
            int   ox = __shfl_down(cx, off);
            if (lane + off < 64) {
                float lp = oi * cd, rp = ci * od;
                if (lp > rp || (lp == rp && ox < cx)) { ci = oi; cd = od; cx = ox; }
            }
        }
        if (lane == 0) { ri[wv][j] = ci; rd[wv][j] = cd; rx[wv][j] = cx; }
    }
    __syncthreads();
    if (threadIdx.x < GPER) {
        int j = threadIdx.x;
        float ci = ri[0][j], cd = rd[0][j]; int cx = rx[0][j];
        for (int w = 1; w < 4; ++w) {
            float oi = ri[w][j], od = rd[w][j]; int ox = rx[w][j];
            float lp = oi * cd, rp = ci * od;
            if (lp > rp || (lp == rp && ox < cx)) { ci = oi; cd = od; cx = ox; }
        }
        float iou = ci / cd;
        unsigned long long key =
            ((unsigned long long)__float_as_uint(iou) << 32) | (unsigned int)(~(unsigned int)cx);
        atomicMax(&wsKey[(size_t)b * G + g0 + j], key);
    }
}

// ---------------- kernel 2b: decode winners -> per-anchor forced flag ----------------
__global__ void kForce(const unsigned long long* __restrict__ wsKey,
                       unsigned char* __restrict__ flag, int A, int G, int BG)
{
    int i = blockIdx.x * 256 + threadIdx.x;
    if (i < BG) {
        unsigned long long k = wsKey[i];
        unsigned int idx = ~(unsigned int)(k & 0xFFFFFFFFull);
        int b = i / G;
        flag[(size_t)b * A + idx] = 1;
    }
}

// ------- kernel 3: per-anchor match + losses, 2 anchors/thread, LDS gt + histogram -------
__global__ __launch_bounds__(256) void kMain(
    const float4* __restrict__ bbox, const float* __restrict__ conf,
    const float4* __restrict__ anchors, const float4* __restrict__ gt,
    const unsigned char* __restrict__ forcedFlag,
    float* __restrict__ neg, int* __restrict__ histC,
    float* __restrict__ accLoc, float* __restrict__ accFpos,
    float* __restrict__ accSiou, int* __restrict__ accNpos,
    int A, int G)
{
    __shared__ float4 sGt[64];
    __shared__ float sGa[64];
    __shared__ int sHist[NBIN];
    __shared__ float red[4][3]; __shared__ int redN[4];
    int b = blockIdx.y;
    for (int i = threadIdx.x; i < NBIN; i += 256) sHist[i] = 0;
    if (threadIdx.x < G) {
        float4 g = gt[(size_t)b * G + threadIdx.x];
        sGt[threadIdx.x] = g;
        sGa[threadIdx.x] = (g.z - g.x) * (g.w - g.y);
    }

    int aBase = blockIdx.x * 512 + threadIdx.x;   // A % 512 == 0
    float4 an[2], p4[2]; float cp[2]; unsigned char ff[2]; float aa[2];
#pragma unroll
    for (int k = 0; k < 2; ++k) {
        int a = aBase + k * 256;
        an[k] = anchors[a];
        p4[k] = bbox[(size_t)b * A + a];
        cp[k] = conf[(size_t)b * A + a];
        ff[k] = forcedFlag[(size_t)b * A + a];
        aa[k] = (an[k].z - an[k].x) * (an[k].w - an[k].y);
    }
    __syncthreads();   // sGt/sGa staged, hist zeroed

    // argmax over g: 4 chains per anchor × 2 anchors = 8 independent chains
    float bi[2][4], bd[2][4]; int bx[2][4];
#pragma unroll
    for (int k = 0; k < 2; ++k)
#pragma unroll
        for (int c = 0; c < 4; ++c) { bi[k][c] = -1.f; bd[k][c] = 1.f; bx[k][c] = c; }
#pragma unroll 2
    for (int g = 0; g < G; g += 4) {
        float4 q0 = sGt[g], q1 = sGt[g + 1], q2 = sGt[g + 2], q3 = sGt[g + 3];
        float4 ga4 = *(const float4*)&sGa[g];
        float qz[4] = {q0.z, q1.z, q2.z, q3.z};
        float qx[4] = {q0.x, q1.x, q2.x, q3.x};
        float qw[4] = {q0.w, q1.w, q2.w, q3.w};
        float qy[4] = {q0.y, q1.y, q2.y, q3.y};
        float gv[4] = {ga4.x, ga4.y, ga4.z, ga4.w};
#pragma unroll
        for (int j = 0; j < 4; ++j) {
#pragma unroll
            for (int k = 0; k < 2; ++k) {
                float wx = fmaxf(fminf(an[k].z, qz[j]) - fmaxf(an[k].x, qx[j]), 0.f);
                float wy = fmaxf(fminf(an[k].w, qw[j]) - fmaxf(an[k].y, qy[j]), 0.f);
                float inter = wx * wy;
                float den = aa[k] + gv[j] - inter + EPSF;
                if (inter * bd[k][j] > bi[k][j] * den) {
                    bi[k][j] = inter; bd[k][j] = den; bx[k][j] = g + j;
                }
            }
        }
    }

    float vloc = 0.f, vf = 0.f, vs = 0.f; int vn = 0;
    bool pos[2]; float Bi[2], Bd[2]; int Bx[2];
#pragma unroll
    for (int k = 0; k < 2; ++k) {
        float ci = bi[k][0], cd = bd[k][0]; int cx = bx[k][0];
#pragma unroll
        for (int c = 1; c < 4; ++c) {
            float lp = bi[k][c] * cd, rp = ci * bd[k][c];
            if (lp > rp || (lp == rp && bx[k][c] < cx)) { ci = bi[k][c]; cd = bd[k][c]; cx = bx[k][c]; }
        }
        Bi[k] = ci; Bd[k] = cd; Bx[k] = cx;
        pos[k] = (ci / cd > IOU_TH) || (ff[k] != 0);
    }
    bool anyPos = __any(pos[0] | pos[1]);
#pragma unroll
    for (int k = 0; k < 2; ++k) {
        float box_loss = 0.f, a_iou = 0.f;
        if (anyPos) {   // wave-uniform: all-negative waves (~95%) skip
            float4 m = sGt[Bx[k]];
            float pa = (p4[k].z - p4[k].x) * (p4[k].w - p4[k].y);
            float ta = (m.z - m.x) * (m.w - m.y);
            float wx = fmaxf(fminf(p4[k].z, m.z) - fmaxf(p4[k].x, m.x), 0.f);
            float wy = fmaxf(fminf(p4[k].w, m.w) - fmaxf(p4[k].y, m.y), 0.f);
            float inter = wx * wy;
            a_iou = inter / (pa + ta - inter + EPSF);
            float ex = fmaxf(fmaxf(p4[k].z, m.z) - fminf(p4[k].x, m.x), 0.f);
            float ey = fmaxf(fmaxf(p4[k].w, m.w) - fminf(p4[k].y, m.y), 0.f);
            float enc = ex * ey + EPSF;
            float uni = pa + ta - a_iou * pa * ta;
            float gl = 1.f - (a_iou - (enc - uni) / enc);
            float cl = sl1((p4[k].x + p4[k].z) * 0.5f - (m.x + m.z) * 0.5f)
                     + sl1((p4[k].y + p4[k].w) * 0.5f - (m.y + m.w) * 0.5f);
            float szl = sl1((p4[k].z - p4[k].x) - (m.z - m.x))
                      + sl1((p4[k].w - p4[k].y) - (m.w - m.y));
            box_loss = 0.5f * (cl + szl) + 0.5f * gl;
        }
        float t = pos[k] ? a_iou : 0.f;
        float pcl = fminf(fmaxf(cp[k], 1e-7f), 1.f - 1e-7f);
        float bce;
        if (anyPos) bce = -(t * logf(pcl) + (1.f - t) * log1pf(-pcl));
        else        bce = -log1pf(-pcl);        // t == 0 exactly
        float pt = (t > 0.f) ? cp[k] : (1.f - cp[k]);
        float om = 1.f - pt;
        float f = om * om * ((t > 0.f) ? 0.25f : 0.75f) * bce;

        neg[(size_t)b * A + aBase + k * 256] = pos[k] ? 0.f : f;
        if (!pos[k]) {
            unsigned int u = __float_as_uint(f);
            atomicAdd(&sHist[u >> 19], 1);
        }
        vloc += pos[k] ? box_loss : 0.f;
        vf   += pos[k] ? f : 0.f;
        vs   += pos[k] ? a_iou : 0.f;
        vn   += pos[k] ? 1 : 0;
    }

    int lane = threadIdx.x & 63, wv = threadIdx.x >> 6;
    for (int off = 32; off > 0; off >>= 1) {
        vloc += __shfl_down(vloc, off);
        vf   += __shfl_down(vf, off);
        vs   += __shfl_down(vs, off);
        vn   += __shfl_down(vn, off);
    }
    if (lane == 0) { red[wv][0] = vloc; red[wv][1] = vf; red[wv][2] = vs; redN[wv] = vn; }
    __syncthreads();   // orders sHist atomics before flush + red[] before sum
    if (threadIdx.x == 0) {
        float sl = 0.f, sf = 0.f, ss = 0.f; int sn = 0;
#pragma unroll
        for (int w = 0; w < 4; ++w) { sl += red[w][0]; sf += red[w][1]; ss += red[w][2]; sn += redN[w]; }
        atomicAdd(&accLoc[b], sl);
        atomicAdd(&accFpos[b], sf);
        atomicAdd(&accSiou[b], ss);
        atomicAdd(&accNpos[b], sn);
    }
    int* hb = histC + (size_t)b * NBIN;
    for (int i = threadIdx.x; i < NBIN; i += 256) {
        int c = sHist[i];
        if (c) atomicAdd(&hb[i], c);
    }
}

// ---------------- kernel 4: top-k sum = hist suffix-scan + one A pass + candidate radix ----
__global__ __launch_bounds__(1024) void kSelect2(
    const float* __restrict__ neg, const int* __restrict__ histC,
    const int* __restrict__ accNpos, const float* __restrict__ accFpos,
    float* __restrict__ cand, float* __restrict__ accConf, int A)
{
    __shared__ int scanI[1024];
    __shared__ float scanF[1024];
    __shared__ int cnt[1024];
    __shared__ float sm[1024];
    __shared__ float redF[16];
    __shared__ int sh_cb, sh_rem, sh_n, sh_done;
    __shared__ float sh_res, sh_sumHigh;

    int b = blockIdx.x;
    int t = threadIdx.x;
    int npos = accNpos[b];
    int k = min(npos * 3, A - npos);
    if (k <= 0) { if (t == 0) accConf[b] = accFpos[b]; return; }

    int4 c4 = ((const int4*)(histC + (size_t)b * NBIN))[t];
    scanI[t] = c4.x + c4.y + c4.z + c4.w;
    __syncthreads();
    for (int off = 1; off < 1024; off <<= 1) {
        int v = (t + off < 1024) ? scanI[t + off] : 0;
        __syncthreads();
        scanI[t] += v;
        __syncthreads();
    }
    {
        int above = (t + 1 < 1024) ? scanI[t + 1] : 0;
        if (above < k && scanI[t] >= k) {
            int carr[4] = {c4.x, c4.y, c4.z, c4.w};
            int cum = above;
            for (int j = 3; j >= 0; --j) {
                cum += carr[j];
                if (cum >= k) { sh_cb = 4 * t + j; sh_rem = k - (cum - carr[j]); break; }
            }
            sh_n = 0; sh_res = 0.f; sh_done = 0;
        }
    }
    __syncthreads();
    int cb = sh_cb;

    float localSum = 0.f;
    const float4* nb4 = (const float4*)(neg + (size_t)b * A);
    float* cb_buf = cand + (size_t)b * A;
    for (int i = t; i < A / 4; i += 1024) {
        float4 v = nb4[i];
        float vv[4] = {v.x, v.y, v.z, v.w};
#pragma unroll
        for (int j = 0; j < 4; ++j) {
            int bin = (int)(__float_as_uint(vv[j]) >> 19);
            if (bin > cb) localSum += vv[j];
            else if (bin == cb) {
                int idx = atomicAdd(&sh_n, 1);
                cb_buf[idx] = vv[j];
            }
        }
    }
    {
        int lane = t & 63, wv = t >> 6;
        for (int off = 32; off > 0; off >>= 1) localSum += __shfl_down(localSum, off);
        if (lane == 0) redF[wv] = localSum;
    }
    __syncthreads();
    if (t == 0) {
        float tot = 0.f;
        for (int w = 0; w < 16; ++w) tot += redF[w];
        sh_sumHigh = tot;
    }
    __syncthreads();
    int n = sh_n;
    int rem = sh_rem;

    cnt[t] = 0; sm[t] = 0.f;
    __syncthreads();
    for (int i = t; i < n; i += 1024) {
        float v = cb_buf[i];
        int bin = (int)((__float_as_uint(v) >> 9) & 1023u);
        atomicAdd(&cnt[bin], 1);
        atomicAdd(&sm[bin], v);
    }
    __syncthreads();
    scanI[t] = cnt[t]; scanF[t] = sm[t];
    __syncthreads();
    for (int off = 1; off < 1024; off <<= 1) {
        int vi = 0; float vf = 0.f;
        if (t + off < 1024) { vi = scanI[t + off]; vf = scanF[t + off]; }
        __syncthreads();
        scanI[t] += vi; scanF[t] += vf;
        __syncthreads();
    }
    {
        int aboveC = (t + 1 < 1024) ? scanI[t + 1] : 0;
        if (aboveC < rem && scanI[t] >= rem) {
            float aboveS = (t + 1 < 1024) ? scanF[t + 1] : 0.f;
            int need = rem - aboveC;
            if (cnt[t] == need) { sh_res += aboveS + sm[t]; sh_done = 1; }
            else { sh_res += aboveS; sh_rem = need; sh_cb = t; }
        }
    }
    __syncthreads();
    if (!sh_done) {
        int cb2 = sh_cb;
        rem = sh_rem;
        if (t < 512) { cnt[t] = 0; sm[t] = 0.f; }
        __syncthreads();
        for (int i = t; i < n; i += 1024) {
            float v = cb_buf[i];
            unsigned int u = __float_as_uint(v);
            if ((int)((u >> 9) & 1023u) == cb2) {
                int bin = (int)(u & 511u);
                atomicAdd(&cnt[bin], 1);
                atomicAdd(&sm[bin], v);
            }
        }
        __syncthreads();
        scanI[t] = (t < 512) ? cnt[t] : 0;
        scanF[t] = (t < 512) ? sm[t] : 0.f;
        __syncthreads();
        for (int off = 1; off < 512; off <<= 1) {
            int vi = 0; float vf = 0.f;
            if (t + off < 512) { vi = scanI[t + off]; vf = scanF[t + off]; }
            __syncthreads();
            if (t < 512) { scanI[t] += vi; scanF[t] += vf; }
            __syncthreads();
        }
        if (t < 512) {
            int aboveC = (t + 1 < 512) ? scanI[t + 1] : 0;
            if (aboveC < rem && scanI[t] >= rem) {
                float aboveS = (t + 1 < 512) ? scanF[t + 1] : 0.f;
                int need = rem - aboveC;
                if (cnt[t] == need) {
                    sh_res += aboveS + sm[t];
                } else {
                    unsigned int u = ((unsigned int)cb << 19) | ((unsigned int)cb2 << 9) | (unsigned int)t;
                    sh_res += aboveS + (float)need * __uint_as_float(u);
                }
            }
        }
        __syncthreads();
    }
    if (t == 0) accConf[b] = sh_sumHigh + sh_res + accFpos[b];
}

// ---------------- kernel 5: final reduce ----------------
__global__ void kFinal(const float* __restrict__ accLoc, const float* __restrict__ accConf,
                       const float* __restrict__ accSiou, const int* __restrict__ accNpos,
                       float* __restrict__ out, int B)
{
    int lane = threadIdx.x;
    float loc = 0.f, cf = 0.f, si = 0.f; int np = 0;
    if (lane < B) { loc = accLoc[lane]; cf = accConf[lane]; si = accSiou[lane]; np = accNpos[lane]; }
    for (int off = 32; off > 0; off >>= 1) {
        loc += __shfl_down(loc, off);
        cf  += __shfl_down(cf, off);
        si  += __shfl_down(si, off);
        np  += __shfl_down(np, off);
    }
    if (lane == 0) {
        float denom = fmaxf(1.f, (float)np);
        float tl = loc / denom, tc = cf / denom;
        out[0] = tl + tc;
        out[1] = tc;
        out[2] = tl;
        out[3] = si / denom;
    }
}

extern "C" void kernel_launch(void* const* d_in, const int* in_sizes, int n_in,
                              void* d_out, int out_size, void* d_ws, size_t ws_size,
                              hipStream_t stream)
{
    const float4* bbox    = (const float4*)d_in[0];
    const float*  conf    = (const float*)d_in[1];
    const float4* anchors = (const float4*)d_in[2];
    const float4* gt      = (const float4*)d_in[3];
    int A = in_sizes[2] / 4;
    int B = in_sizes[1] / A;
    int G = in_sizes[3] / (4 * B);
    float* out = (float*)d_out;

    char* ws = (char*)d_ws;
    size_t off = 0;
    float* neg  = (float*)(ws + off); off += (size_t)B * A * sizeof(float);
    float* cand = (float*)(ws + off); off += (size_t)B * A * sizeof(float);
    size_t zOff = off;
    unsigned char* forcedFlag = (unsigned char*)(ws + off); off += (size_t)B * A;
    unsigned long long* wsKey = (unsigned long long*)(ws + off); off += (size_t)B * G * 8;
    int* histC = (int*)(ws + off); off += (size_t)B * NBIN * sizeof(int);
    float* accLoc  = (float*)(ws + off); off += (size_t)B * sizeof(float);
    float* accFpos = (float*)(ws + off); off += (size_t)B * sizeof(float);
    float* accSiou = (float*)(ws + off); off += (size_t)B * sizeof(float);
    float* accConf = (float*)(ws + off); off += (size_t)B * sizeof(float);
    int*   accNpos = (int*)(ws + off);   off += (size_t)B * sizeof(int);
    size_t zBytes = off - zOff;

    hipMemsetAsync(ws + zOff, 0, zBytes, stream);

    int nch = G / GPER;
    kBestAnchor<<<dim3(B * nch * ASPLIT), 256, 0, stream>>>(anchors, gt, wsKey, A, G);
    int BG = B * G;
    kForce<<<dim3((BG + 255) / 256), 256, 0, stream>>>(wsKey, forcedFlag, A, G, BG);
    kMain<<<dim3(A / 512, B), 256, 0, stream>>>(bbox, conf, anchors, gt, forcedFlag,
                                                neg, histC, accLoc, accFpos, accSiou, accNpos, A, G);
    kSelect2<<<dim3(B), 1024, 0, stream>>>(neg, histC, accNpos, accFpos, cand, accConf, A);
    kFinal<<<1, 64, 0, stream>>>(accLoc, accConf, accSiou, accNpos, out, B);
}

// Round 7
// 79.114 us; speedup vs baseline: 1.3027x; 1.0070x over previous
//
#include <hip/hip_runtime.h>
#include <math.h>

#define IOU_TH 0.5f
#define EPSF 1e-6f
#define GPER 8
#define ASPLIT 16
#define NBIN 4096

__device__ __forceinline__ float sl1(float x) {
    float ax = fabsf(x);
    return ax < 1.f ? 0.5f * x * x : ax - 0.5f;
}

// ---------------- kernel 0: workspace zeroing (rocclr fillBuffer is ~39us for this!) ----
__global__ __launch_bounds__(256) void kZero(uint4* __restrict__ p, int n16)
{
    int i = blockIdx.x * 256 + threadIdx.x;
    if (i < n16) p[i] = make_uint4(0u, 0u, 0u, 0u);
}

// ---------------- kernel 2: best anchor per (b,g), A split 16-way, merged via atomicMax ----
__global__ __launch_bounds__(256) void kBestAnchor(
    const float4* __restrict__ anchors, const float4* __restrict__ gt,
    unsigned long long* __restrict__ wsKey, int A, int G)
{
    int nch = G / GPER;
    int b   = blockIdx.x / (nch * ASPLIT);
    int r   = blockIdx.x % (nch * ASPLIT);
    int g0  = (r / ASPLIT) * GPER;
    int aChunk = A / ASPLIT;
    int a0  = (r % ASPLIT) * aChunk;

    float4 gb[GPER]; float ga[GPER];
#pragma unroll
    for (int j = 0; j < GPER; ++j) {
        gb[j] = gt[(size_t)b * G + g0 + j];
        ga[j] = (gb[j].z - gb[j].x) * (gb[j].w - gb[j].y);
    }
    float bi[GPER], bd[GPER]; int bx[GPER];
#pragma unroll
    for (int j = 0; j < GPER; ++j) { bi[j] = -1.f; bd[j] = 1.f; bx[j] = a0; }
    for (int a = a0 + threadIdx.x; a < a0 + aChunk; a += 256) {
        float4 ab = anchors[a];
        float aa = (ab.z - ab.x) * (ab.w - ab.y);
#pragma unroll
        for (int j = 0; j < GPER; ++j) {
            float wx = fmaxf(fminf(ab.z, gb[j].z) - fmaxf(ab.x, gb[j].x), 0.f);
            float wy = fmaxf(fminf(ab.w, gb[j].w) - fmaxf(ab.y, gb[j].y), 0.f);
            float inter = wx * wy;
            float den = aa + ga[j] - inter + EPSF;
            if (inter * bd[j] > bi[j] * den) { bi[j] = inter; bd[j] = den; bx[j] = a; }
        }
    }
    int lane = threadIdx.x & 63, wv = threadIdx.x >> 6;
    __shared__ float ri[4][GPER], rd[4][GPER]; __shared__ int rx[4][GPER];
#pragma unroll
    for (int j = 0; j < GPER; ++j) {
        float ci = bi[j], cd = bd[j]; int cx = bx[j];
        for (int off = 32; off > 0; off >>= 1) {
            float oi = __shfl_down(ci, off);
            float od = __shfl_down(cd, off);
            int   ox = __shfl_down(cx, off);
            if (lane + off < 64) {
                float lp = oi * cd, rp = ci * od;
                if (lp > rp || (lp == rp && ox < cx)) { ci = oi; cd = od; cx = ox; }
            }
        }
        if (lane == 0) { ri[wv][j] = ci; rd[wv][j] = cd; rx[wv][j] = cx; }
    }
    __syncthreads();
    if (threadIdx.x < GPER) {
        int j = threadIdx.x;
        float ci = ri[0][j], cd = rd[0][j]; int cx = rx[0][j];
        for (int w = 1; w < 4; ++w) {
            float oi = ri[w][j], od = rd[w][j]; int ox = rx[w][j];
            float lp = oi * cd, rp = ci * od;
            if (lp > rp || (lp == rp && ox < cx)) { ci = oi; cd = od; cx = ox; }
        }
        float iou = ci / cd;
        unsigned long long key =
            ((unsigned long long)__float_as_uint(iou) << 32) | (unsigned int)(~(unsigned int)cx);
        atomicMax(&wsKey[(size_t)b * G + g0 + j], key);
    }
}

// ---------------- kernel 2b: decode winners -> per-anchor forced flag ----------------
__global__ void kForce(const unsigned long long* __restrict__ wsKey,
                       unsigned char* __restrict__ flag, int A, int G, int BG)
{
    int i = blockIdx.x * 256 + threadIdx.x;
    if (i < BG) {
        unsigned long long k = wsKey[i];
        unsigned int idx = ~(unsigned int)(k & 0xFFFFFFFFull);
        int b = i / G;
        flag[(size_t)b * A + idx] = 1;
    }
}

// ------- kernel 3: per-anchor match + losses, 2 anchors/thread, LDS gt + histogram -------
__global__ __launch_bounds__(256) void kMain(
    const float4* __restrict__ bbox, const float* __restrict__ conf,
    const float4* __restrict__ anchors, const float4* __restrict__ gt,
    const unsigned char* __restrict__ forcedFlag,
    float* __restrict__ neg, int* __restrict__ histC,
    float* __restrict__ accLoc, float* __restrict__ accFpos,
    float* __restrict__ accSiou, int* __restrict__ accNpos,
    int A, int G)
{
    __shared__ float4 sGt[64];
    __shared__ float sGa[64];
    __shared__ int sHist[NBIN];
    __shared__ float red[4][3]; __shared__ int redN[4];
    int b = blockIdx.y;
    for (int i = threadIdx.x; i < NBIN; i += 256) sHist[i] = 0;
    if (threadIdx.x < G) {
        float4 g = gt[(size_t)b * G + threadIdx.x];
        sGt[threadIdx.x] = g;
        sGa[threadIdx.x] = (g.z - g.x) * (g.w - g.y);
    }

    int aBase = blockIdx.x * 512 + threadIdx.x;   // A % 512 == 0
    float4 an[2], p4[2]; float cp[2]; unsigned char ff[2]; float aa[2];
#pragma unroll
    for (int k = 0; k < 2; ++k) {
        int a = aBase + k * 256;
        an[k] = anchors[a];
        p4[k] = bbox[(size_t)b * A + a];
        cp[k] = conf[(size_t)b * A + a];
        ff[k] = forcedFlag[(size_t)b * A + a];
        aa[k] = (an[k].z - an[k].x) * (an[k].w - an[k].y);
    }
    __syncthreads();   // sGt/sGa staged, hist zeroed

    // argmax over g: 4 chains per anchor × 2 anchors = 8 independent chains
    float bi[2][4], bd[2][4]; int bx[2][4];
#pragma unroll
    for (int k = 0; k < 2; ++k)
#pragma unroll
        for (int c = 0; c < 4; ++c) { bi[k][c] = -1.f; bd[k][c] = 1.f; bx[k][c] = c; }
#pragma unroll 2
    for (int g = 0; g < G; g += 4) {
        float4 q0 = sGt[g], q1 = sGt[g + 1], q2 = sGt[g + 2], q3 = sGt[g + 3];
        float4 ga4 = *(const float4*)&sGa[g];
        float qz[4] = {q0.z, q1.z, q2.z, q3.z};
        float qx[4] = {q0.x, q1.x, q2.x, q3.x};
        float qw[4] = {q0.w, q1.w, q2.w, q3.w};
        float qy[4] = {q0.y, q1.y, q2.y, q3.y};
        float gv[4] = {ga4.x, ga4.y, ga4.z, ga4.w};
#pragma unroll
        for (int j = 0; j < 4; ++j) {
#pragma unroll
            for (int k = 0; k < 2; ++k) {
                float wx = fmaxf(fminf(an[k].z, qz[j]) - fmaxf(an[k].x, qx[j]), 0.f);
                float wy = fmaxf(fminf(an[k].w, qw[j]) - fmaxf(an[k].y, qy[j]), 0.f);
                float inter = wx * wy;
                float den = aa[k] + gv[j] - inter + EPSF;
                if (inter * bd[k][j] > bi[k][j] * den) {
                    bi[k][j] = inter; bd[k][j] = den; bx[k][j] = g + j;
                }
            }
        }
    }

    float vloc = 0.f, vf = 0.f, vs = 0.f; int vn = 0;
    bool pos[2]; float Bi[2], Bd[2]; int Bx[2];
#pragma unroll
    for (int k = 0; k < 2; ++k) {
        float ci = bi[k][0], cd = bd[k][0]; int cx = bx[k][0];
#pragma unroll
        for (int c = 1; c < 4; ++c) {
            float lp = bi[k][c] * cd, rp = ci * bd[k][c];
            if (lp > rp || (lp == rp && bx[k][c] < cx)) { ci = bi[k][c]; cd = bd[k][c]; cx = bx[k][c]; }
        }
        Bi[k] = ci; Bd[k] = cd; Bx[k] = cx;
        pos[k] = (ci / cd > IOU_TH) || (ff[k] != 0);
    }
    bool anyPos = __any(pos[0] | pos[1]);
#pragma unroll
    for (int k = 0; k < 2; ++k) {
        float box_loss = 0.f, a_iou = 0.f;
        if (anyPos) {   // wave-uniform: all-negative waves (~95%) skip
            float4 m = sGt[Bx[k]];
            float pa = (p4[k].z - p4[k].x) * (p4[k].w - p4[k].y);
            float ta = (m.z - m.x) * (m.w - m.y);
            float wx = fmaxf(fminf(p4[k].z, m.z) - fmaxf(p4[k].x, m.x), 0.f);
            float wy = fmaxf(fminf(p4[k].w, m.w) - fmaxf(p4[k].y, m.y), 0.f);
            float inter = wx * wy;
            a_iou = inter / (pa + ta - inter + EPSF);
            float ex = fmaxf(fmaxf(p4[k].z, m.z) - fminf(p4[k].x, m.x), 0.f);
            float ey = fmaxf(fmaxf(p4[k].w, m.w) - fminf(p4[k].y, m.y), 0.f);
            float enc = ex * ey + EPSF;
            float uni = pa + ta - a_iou * pa * ta;
            float gl = 1.f - (a_iou - (enc - uni) / enc);
            float cl = sl1((p4[k].x + p4[k].z) * 0.5f - (m.x + m.z) * 0.5f)
                     + sl1((p4[k].y + p4[k].w) * 0.5f - (m.y + m.w) * 0.5f);
            float szl = sl1((p4[k].z - p4[k].x) - (m.z - m.x))
                      + sl1((p4[k].w - p4[k].y) - (m.w - m.y));
            box_loss = 0.5f * (cl + szl) + 0.5f * gl;
        }
        float t = pos[k] ? a_iou : 0.f;
        float pcl = fminf(fmaxf(cp[k], 1e-7f), 1.f - 1e-7f);
        float bce;
        if (anyPos) bce = -(t * logf(pcl) + (1.f - t) * log1pf(-pcl));
        else        bce = -log1pf(-pcl);        // t == 0 exactly
        float pt = (t > 0.f) ? cp[k] : (1.f - cp[k]);
        float om = 1.f - pt;
        float f = om * om * ((t > 0.f) ? 0.25f : 0.75f) * bce;

        neg[(size_t)b * A + aBase + k * 256] = pos[k] ? 0.f : f;
        if (!pos[k]) {
            unsigned int u = __float_as_uint(f);
            atomicAdd(&sHist[u >> 19], 1);
        }
        vloc += pos[k] ? box_loss : 0.f;
        vf   += pos[k] ? f : 0.f;
        vs   += pos[k] ? a_iou : 0.f;
        vn   += pos[k] ? 1 : 0;
    }

    int lane = threadIdx.x & 63, wv = threadIdx.x >> 6;
    for (int off = 32; off > 0; off >>= 1) {
        vloc += __shfl_down(vloc, off);
        vf   += __shfl_down(vf, off);
        vs   += __shfl_down(vs, off);
        vn   += __shfl_down(vn, off);
    }
    if (lane == 0) { red[wv][0] = vloc; red[wv][1] = vf; red[wv][2] = vs; redN[wv] = vn; }
    __syncthreads();   // orders sHist atomics before flush + red[] before sum
    if (threadIdx.x == 0) {
        float sl = 0.f, sf = 0.f, ss = 0.f; int sn = 0;
#pragma unroll
        for (int w = 0; w < 4; ++w) { sl += red[w][0]; sf += red[w][1]; ss += red[w][2]; sn += redN[w]; }
        atomicAdd(&accLoc[b], sl);
        atomicAdd(&accFpos[b], sf);
        atomicAdd(&accSiou[b], ss);
        atomicAdd(&accNpos[b], sn);
    }
    int* hb = histC + (size_t)b * NBIN;
    for (int i = threadIdx.x; i < NBIN; i += 256) {
        int c = sHist[i];
        if (c) atomicAdd(&hb[i], c);
    }
}

// ---------------- kernel 4: top-k sum = hist suffix-scan + one A pass + candidate radix ----
__global__ __launch_bounds__(1024) void kSelect2(
    const float* __restrict__ neg, const int* __restrict__ histC,
    const int* __restrict__ accNpos, const float* __restrict__ accFpos,
    float* __restrict__ cand, float* __restrict__ accConf, int A)
{
    __shared__ int scanI[1024];
    __shared__ float scanF[1024];
    __shared__ int cnt[1024];
    __shared__ float sm[1024];
    __shared__ float redF[16];
    __shared__ int sh_cb, sh_rem, sh_n, sh_done;
    __shared__ float sh_res, sh_sumHigh;

    int b = blockIdx.x;
    int t = threadIdx.x;
    int npos = accNpos[b];
    int k = min(npos * 3, A - npos);
    if (k <= 0) { if (t == 0) accConf[b] = accFpos[b]; return; }

    int4 c4 = ((const int4*)(histC + (size_t)b * NBIN))[t];
    scanI[t] = c4.x + c4.y + c4.z + c4.w;
    __syncthreads();
    for (int off = 1; off < 1024; off <<= 1) {
        int v = (t + off < 1024) ? scanI[t + off] : 0;
        __syncthreads();
        scanI[t] += v;
        __syncthreads();
    }
    {
        int above = (t + 1 < 1024) ? scanI[t + 1] : 0;
        if (above < k && scanI[t] >= k) {
            int carr[4] = {c4.x, c4.y, c4.z, c4.w};
            int cum = above;
            for (int j = 3; j >= 0; --j) {
                cum += carr[j];
                if (cum >= k) { sh_cb = 4 * t + j; sh_rem = k - (cum - carr[j]); break; }
            }
            sh_n = 0; sh_res = 0.f; sh_done = 0;
        }
    }
    __syncthreads();
    int cb = sh_cb;

    float localSum = 0.f;
    const float4* nb4 = (const float4*)(neg + (size_t)b * A);
    float* cb_buf = cand + (size_t)b * A;
    for (int i = t; i < A / 4; i += 1024) {
        float4 v = nb4[i];
        float vv[4] = {v.x, v.y, v.z, v.w};
#pragma unroll
        for (int j = 0; j < 4; ++j) {
            int bin = (int)(__float_as_uint(vv[j]) >> 19);
            if (bin > cb) localSum += vv[j];
            else if (bin == cb) {
                int idx = atomicAdd(&sh_n, 1);
                cb_buf[idx] = vv[j];
            }
        }
    }
    {
        int lane = t & 63, wv = t >> 6;
        for (int off = 32; off > 0; off >>= 1) localSum += __shfl_down(localSum, off);
        if (lane == 0) redF[wv] = localSum;
    }
    __syncthreads();
    if (t == 0) {
        float tot = 0.f;
        for (int w = 0; w < 16; ++w) tot += redF[w];
        sh_sumHigh = tot;
    }
    __syncthreads();
    int n = sh_n;
    int rem = sh_rem;

    cnt[t] = 0; sm[t] = 0.f;
    __syncthreads();
    for (int i = t; i < n; i += 1024) {
        float v = cb_buf[i];
        int bin = (int)((__float_as_uint(v) >> 9) & 1023u);
        atomicAdd(&cnt[bin], 1);
        atomicAdd(&sm[bin], v);
    }
    __syncthreads();
    scanI[t] = cnt[t]; scanF[t] = sm[t];
    __syncthreads();
    for (int off = 1; off < 1024; off <<= 1) {
        int vi = 0; float vf = 0.f;
        if (t + off < 1024) { vi = scanI[t + off]; vf = scanF[t + off]; }
        __syncthreads();
        scanI[t] += vi; scanF[t] += vf;
        __syncthreads();
    }
    {
        int aboveC = (t + 1 < 1024) ? scanI[t + 1] : 0;
        if (aboveC < rem && scanI[t] >= rem) {
            float aboveS = (t + 1 < 1024) ? scanF[t + 1] : 0.f;
            int need = rem - aboveC;
            if (cnt[t] == need) { sh_res += aboveS + sm[t]; sh_done = 1; }
            else { sh_res += aboveS; sh_rem = need; sh_cb = t; }
        }
    }
    __syncthreads();
    if (!sh_done) {
        int cb2 = sh_cb;
        rem = sh_rem;
        if (t < 512) { cnt[t] = 0; sm[t] = 0.f; }
        __syncthreads();
        for (int i = t; i < n; i += 1024) {
            float v = cb_buf[i];
            unsigned int u = __float_as_uint(v);
            if ((int)((u >> 9) & 1023u) == cb2) {
                int bin = (int)(u & 511u);
                atomicAdd(&cnt[bin], 1);
                atomicAdd(&sm[bin], v);
            }
        }
        __syncthreads();
        scanI[t] = (t < 512) ? cnt[t] : 0;
        scanF[t] = (t < 512) ? sm[t] : 0.f;
        __syncthreads();
        for (int off = 1; off < 512; off <<= 1) {
            int vi = 0; float vf = 0.f;
            if (t + off < 512) { vi = scanI[t + off]; vf = scanF[t + off]; }
            __syncthreads();
            if (t < 512) { scanI[t] += vi; scanF[t] += vf; }
            __syncthreads();
        }
        if (t < 512) {
            int aboveC = (t + 1 < 512) ? scanI[t + 1] : 0;
            if (aboveC < rem && scanI[t] >= rem) {
                float aboveS = (t + 1 < 512) ? scanF[t + 1] : 0.f;
                int need = rem - aboveC;
                if (cnt[t] == need) {
                    sh_res += aboveS + sm[t];
                } else {
                    unsigned int u = ((unsigned int)cb << 19) | ((unsigned int)cb2 << 9) | (unsigned int)t;
                    sh_res += aboveS + (float)need * __uint_as_float(u);
                }
            }
        }
        __syncthreads();
    }
    if (t == 0) accConf[b] = sh_sumHigh + sh_res + accFpos[b];
}

// ---------------- kernel 5: final reduce ----------------
__global__ void kFinal(const float* __restrict__ accLoc, const float* __restrict__ accConf,
                       const float* __restrict__ accSiou, const int* __restrict__ accNpos,
                       float* __restrict__ out, int B)
{
    int lane = threadIdx.x;
    float loc = 0.f, cf = 0.f, si = 0.f; int np = 0;
    if (lane < B) { loc = accLoc[lane]; cf = accConf[lane]; si = accSiou[lane]; np = accNpos[lane]; }
    for (int off = 32; off > 0; off >>= 1) {
        loc += __shfl_down(loc, off);
        cf  += __shfl_down(cf, off);
        si  += __shfl_down(si, off);
        np  += __shfl_down(np, off);
    }
    if (lane == 0) {
        float denom = fmaxf(1.f, (float)np);
        float tl = loc / denom, tc = cf / denom;
        out[0] = tl + tc;
        out[1] = tc;
        out[2] = tl;
        out[3] = si / denom;
    }
}

extern "C" void kernel_launch(void* const* d_in, const int* in_sizes, int n_in,
                              void* d_out, int out_size, void* d_ws, size_t ws_size,
                              hipStream_t stream)
{
    const float4* bbox    = (const float4*)d_in[0];
    const float*  conf    = (const float*)d_in[1];
    const float4* anchors = (const float4*)d_in[2];
    const float4* gt      = (const float4*)d_in[3];
    int A = in_sizes[2] / 4;
    int B = in_sizes[1] / A;
    int G = in_sizes[3] / (4 * B);
    float* out = (float*)d_out;

    char* ws = (char*)d_ws;
    size_t off = 0;
    float* neg  = (float*)(ws + off); off += (size_t)B * A * sizeof(float);
    float* cand = (float*)(ws + off); off += (size_t)B * A * sizeof(float);
    size_t zOff = off;
    unsigned char* forcedFlag = (unsigned char*)(ws + off); off += (size_t)B * A;
    unsigned long long* wsKey = (unsigned long long*)(ws + off); off += (size_t)B * G * 8;
    int* histC = (int*)(ws + off); off += (size_t)B * NBIN * sizeof(int);
    float* accLoc  = (float*)(ws + off); off += (size_t)B * sizeof(float);
    float* accFpos = (float*)(ws + off); off += (size_t)B * sizeof(float);
    float* accSiou = (float*)(ws + off); off += (size_t)B * sizeof(float);
    float* accConf = (float*)(ws + off); off += (size_t)B * sizeof(float);
    int*   accNpos = (int*)(ws + off);   off += (size_t)B * sizeof(int);
    size_t zBytes = off - zOff;          // 16-byte divisible by construction

    int n16 = (int)(zBytes / 16);
    kZero<<<dim3((n16 + 255) / 256), 256, 0, stream>>>((uint4*)(ws + zOff), n16);

    int nch = G / GPER;
    kBestAnchor<<<dim3(B * nch * ASPLIT), 256, 0, stream>>>(anchors, gt, wsKey, A, G);
    int BG = B * G;
    kForce<<<dim3((BG + 255) / 256), 256, 0, stream>>>(wsKey, forcedFlag, A, G, BG);
    kMain<<<dim3(A / 512, B), 256, 0, stream>>>(bbox, conf, anchors, gt, forcedFlag,
                                                neg, histC, accLoc, accFpos, accSiou, accNpos, A, G);
    kSelect2<<<dim3(B), 1024, 0, stream>>>(neg, histC, accNpos, accFpos, cand, accConf, A);
    kFinal<<<1, 64, 0, stream>>>(accLoc, accConf, accSiou, accNpos, out, B);
}

// Round 8
// 73.667 us; speedup vs baseline: 1.3990x; 1.0739x over previous
//
#include <hip/hip_runtime.h>
#include <math.h>

#define IOU_TH 0.5f
#define EPSF 1e-6f
#define GPER 8
#define ASPLIT 16
#define NBIN 4096

__device__ __forceinline__ float sl1(float x) {
    float ax = fabsf(x);
    return ax < 1.f ? 0.5f * x * x : ax - 0.5f;
}

__device__ __forceinline__ unsigned long long umax64(unsigned long long a, unsigned long long b) {
    return a > b ? a : b;
}

// ---- kernel 1: best anchor per (b,g,part) -> plain store; side duty: zero histC + acc ----
__global__ __launch_bounds__(256) void kBestAnchor(
    const float4* __restrict__ anchors, const float4* __restrict__ gt,
    unsigned long long* __restrict__ wsKeyPart,
    uint4* __restrict__ histZero, uint4* __restrict__ accZero,
    int A, int G)
{
    // zero duty: 2048 blocks x 8 uint4 = histC (256KB); block 0 also zeroes acc block (512B)
    if (threadIdx.x < 8) histZero[blockIdx.x * 8 + threadIdx.x] = make_uint4(0u, 0u, 0u, 0u);
    if (blockIdx.x == 0 && threadIdx.x >= 64 && threadIdx.x < 96)
        accZero[threadIdx.x - 64] = make_uint4(0u, 0u, 0u, 0u);

    int nch = G / GPER;
    int b   = blockIdx.x / (nch * ASPLIT);
    int r   = blockIdx.x % (nch * ASPLIT);
    int g0  = (r / ASPLIT) * GPER;
    int part = r % ASPLIT;
    int aChunk = A / ASPLIT;
    int a0  = part * aChunk;

    float4 gb[GPER]; float ga[GPER];
#pragma unroll
    for (int j = 0; j < GPER; ++j) {
        gb[j] = gt[(size_t)b * G + g0 + j];
        ga[j] = (gb[j].z - gb[j].x) * (gb[j].w - gb[j].y);
    }
    float bi[GPER], bd[GPER]; int bx[GPER];
#pragma unroll
    for (int j = 0; j < GPER; ++j) { bi[j] = -1.f; bd[j] = 1.f; bx[j] = a0; }
    for (int a = a0 + threadIdx.x; a < a0 + aChunk; a += 256) {
        float4 ab = anchors[a];
        float aa = (ab.z - ab.x) * (ab.w - ab.y);
#pragma unroll
        for (int j = 0; j < GPER; ++j) {
            float wx = fmaxf(fminf(ab.z, gb[j].z) - fmaxf(ab.x, gb[j].x), 0.f);
            float wy = fmaxf(fminf(ab.w, gb[j].w) - fmaxf(ab.y, gb[j].y), 0.f);
            float inter = wx * wy;
            float den = aa + ga[j] - inter + EPSF;
            if (inter * bd[j] > bi[j] * den) { bi[j] = inter; bd[j] = den; bx[j] = a; }
        }
    }
    int lane = threadIdx.x & 63, wv = threadIdx.x >> 6;
    __shared__ float ri[4][GPER], rd[4][GPER]; __shared__ int rx[4][GPER];
#pragma unroll
    for (int j = 0; j < GPER; ++j) {
        float ci = bi[j], cd = bd[j]; int cx = bx[j];
        for (int off = 32; off > 0; off >>= 1) {
            float oi = __shfl_down(ci, off);
            float od = __shfl_down(cd, off);
            int   ox = __shfl_down(cx, off);
            if (lane + off < 64) {
                float lp = oi * cd, rp = ci * od;
                if (lp > rp || (lp == rp && ox < cx)) { ci = oi; cd = od; cx = ox; }
            }
        }
        if (lane == 0) { ri[wv][j] = ci; rd[wv][j] = cd; rx[wv][j] = cx; }
    }
    __syncthreads();
    if (threadIdx.x < GPER) {
        int j = threadIdx.x;
        float ci = ri[0][j], cd = rd[0][j]; int cx = rx[0][j];
        for (int w = 1; w < 4; ++w) {
            float oi = ri[w][j], od = rd[w][j]; int ox = rx[w][j];
            float lp = oi * cd, rp = ci * od;
            if (lp > rp || (lp == rp && ox < cx)) { ci = oi; cd = od; cx = ox; }
        }
        float iou = ci / cd;   // divided value compared across parts (matches jnp semantics)
        unsigned long long key =
            ((unsigned long long)__float_as_uint(iou) << 32) | (unsigned int)(~(unsigned int)cx);
        wsKeyPart[((size_t)b * G + g0 + j) * ASPLIT + part] = key;   // plain store, no init needed
    }
}

// ------- kernel 2: per-anchor match + losses, 2 anchors/thread, in-kernel winner decode ----
__global__ __launch_bounds__(256) void kMain(
    const float4* __restrict__ bbox, const float* __restrict__ conf,
    const float4* __restrict__ anchors, const float4* __restrict__ gt,
    const unsigned long long* __restrict__ wsKeyPart,
    float* __restrict__ neg, int* __restrict__ histC,
    float* __restrict__ accLoc, float* __restrict__ accFpos,
    float* __restrict__ accSiou, int* __restrict__ accNpos,
    int A, int G)
{
    __shared__ float4 sGt[64];
    __shared__ float sGa[64];
    __shared__ int sHist[NBIN];
    __shared__ unsigned long long sKeyQ[256];
    __shared__ unsigned char sPosFlag[512];
    __shared__ float red[4][3]; __shared__ int redN[4];
    int b = blockIdx.y;
    for (int i = threadIdx.x; i < NBIN; i += 256) sHist[i] = 0;
    sPosFlag[threadIdx.x] = 0;
    sPosFlag[threadIdx.x + 256] = 0;
    if (threadIdx.x < G) {
        float4 g = gt[(size_t)b * G + threadIdx.x];
        sGt[threadIdx.x] = g;
        sGa[threadIdx.x] = (g.z - g.x) * (g.w - g.y);
    }
    // winner decode stage 1: thread t covers gt (t>>2), parts 4*(t&3)..+3
    {
        int g = threadIdx.x >> 2, p0 = (threadIdx.x & 3) * 4;
        const unsigned long long* kp = wsKeyPart + ((size_t)b * G + g) * ASPLIT + p0;
        unsigned long long m = umax64(umax64(kp[0], kp[1]), umax64(kp[2], kp[3]));
        sKeyQ[threadIdx.x] = m;
    }

    int aBase = blockIdx.x * 512 + threadIdx.x;   // A % 512 == 0
    float4 an[2], p4[2]; float cp[2]; float aa[2];
#pragma unroll
    for (int k = 0; k < 2; ++k) {
        int a = aBase + k * 256;
        an[k] = anchors[a];
        p4[k] = bbox[(size_t)b * A + a];
        cp[k] = conf[(size_t)b * A + a];
        aa[k] = (an[k].z - an[k].x) * (an[k].w - an[k].y);
    }
    __syncthreads();   // sKeyQ + sGt/sGa + zeroed flags visible
    // winner decode stage 2: t<64 reduces 4 quads, flags winners inside this block's range
    if (threadIdx.x < 64) {
        int t4 = threadIdx.x * 4;
        unsigned long long m = umax64(umax64(sKeyQ[t4], sKeyQ[t4 + 1]),
                                      umax64(sKeyQ[t4 + 2], sKeyQ[t4 + 3]));
        unsigned int idx = ~(unsigned int)(m & 0xFFFFFFFFull);
        unsigned int local = idx - (unsigned int)(blockIdx.x * 512);
        if (local < 512u) sPosFlag[local] = 1;
    }
    __syncthreads();   // flags ready

    // argmax over g: 4 chains per anchor x 2 anchors = 8 independent chains
    float bi[2][4], bd[2][4]; int bx[2][4];
#pragma unroll
    for (int k = 0; k < 2; ++k)
#pragma unroll
        for (int c = 0; c < 4; ++c) { bi[k][c] = -1.f; bd[k][c] = 1.f; bx[k][c] = c; }
#pragma unroll 2
    for (int g = 0; g < G; g += 4) {
        float4 q0 = sGt[g], q1 = sGt[g + 1], q2 = sGt[g + 2], q3 = sGt[g + 3];
        float4 ga4 = *(const float4*)&sGa[g];
        float qz[4] = {q0.z, q1.z, q2.z, q3.z};
        float qx[4] = {q0.x, q1.x, q2.x, q3.x};
        float qw[4] = {q0.w, q1.w, q2.w, q3.w};
        float qy[4] = {q0.y, q1.y, q2.y, q3.y};
        float gv[4] = {ga4.x, ga4.y, ga4.z, ga4.w};
#pragma unroll
        for (int j = 0; j < 4; ++j) {
#pragma unroll
            for (int k = 0; k < 2; ++k) {
                float wx = fmaxf(fminf(an[k].z, qz[j]) - fmaxf(an[k].x, qx[j]), 0.f);
                float wy = fmaxf(fminf(an[k].w, qw[j]) - fmaxf(an[k].y, qy[j]), 0.f);
                float inter = wx * wy;
                float den = aa[k] + gv[j] - inter + EPSF;
                if (inter * bd[k][j] > bi[k][j] * den) {
                    bi[k][j] = inter; bd[k][j] = den; bx[k][j] = g + j;
                }
            }
        }
    }

    float vloc = 0.f, vf = 0.f, vs = 0.f; int vn = 0;
    bool pos[2]; int Bx[2];
#pragma unroll
    for (int k = 0; k < 2; ++k) {
        float ci = bi[k][0], cd = bd[k][0]; int cx = bx[k][0];
#pragma unroll
        for (int c = 1; c < 4; ++c) {
            float lp = bi[k][c] * cd, rp = ci * bd[k][c];
            if (lp > rp || (lp == rp && bx[k][c] < cx)) { ci = bi[k][c]; cd = bd[k][c]; cx = bx[k][c]; }
        }
        Bx[k] = cx;
        pos[k] = (ci / cd > IOU_TH) || (sPosFlag[threadIdx.x + k * 256] != 0);
    }
    bool anyPos = __any(pos[0] | pos[1]);
#pragma unroll
    for (int k = 0; k < 2; ++k) {
        float box_loss = 0.f, a_iou = 0.f;
        if (anyPos) {   // wave-uniform: all-negative waves (~95%) skip
            float4 m = sGt[Bx[k]];
            float pa = (p4[k].z - p4[k].x) * (p4[k].w - p4[k].y);
            float ta = (m.z - m.x) * (m.w - m.y);
            float wx = fmaxf(fminf(p4[k].z, m.z) - fmaxf(p4[k].x, m.x), 0.f);
            float wy = fmaxf(fminf(p4[k].w, m.w) - fmaxf(p4[k].y, m.y), 0.f);
            float inter = wx * wy;
            a_iou = inter / (pa + ta - inter + EPSF);
            float ex = fmaxf(fmaxf(p4[k].z, m.z) - fminf(p4[k].x, m.x), 0.f);
            float ey = fmaxf(fmaxf(p4[k].w, m.w) - fminf(p4[k].y, m.y), 0.f);
            float enc = ex * ey + EPSF;
            float uni = pa + ta - a_iou * pa * ta;
            float gl = 1.f - (a_iou - (enc - uni) / enc);
            float cl = sl1((p4[k].x + p4[k].z) * 0.5f - (m.x + m.z) * 0.5f)
                     + sl1((p4[k].y + p4[k].w) * 0.5f - (m.y + m.w) * 0.5f);
            float szl = sl1((p4[k].z - p4[k].x) - (m.z - m.x))
                      + sl1((p4[k].w - p4[k].y) - (m.w - m.y));
            box_loss = 0.5f * (cl + szl) + 0.5f * gl;
        }
        float t = pos[k] ? a_iou : 0.f;
        float pcl = fminf(fmaxf(cp[k], 1e-7f), 1.f - 1e-7f);
        float bce;
        if (anyPos) bce = -(t * logf(pcl) + (1.f - t) * log1pf(-pcl));
        else        bce = -log1pf(-pcl);        // t == 0 exactly
        float pt = (t > 0.f) ? cp[k] : (1.f - cp[k]);
        float om = 1.f - pt;
        float f = om * om * ((t > 0.f) ? 0.25f : 0.75f) * bce;

        neg[(size_t)b * A + aBase + k * 256] = pos[k] ? 0.f : f;
        if (!pos[k]) {
            unsigned int u = __float_as_uint(f);
            atomicAdd(&sHist[u >> 19], 1);
        }
        vloc += pos[k] ? box_loss : 0.f;
        vf   += pos[k] ? f : 0.f;
        vs   += pos[k] ? a_iou : 0.f;
        vn   += pos[k] ? 1 : 0;
    }

    int lane = threadIdx.x & 63, wv = threadIdx.x >> 6;
    for (int off = 32; off > 0; off >>= 1) {
        vloc += __shfl_down(vloc, off);
        vf   += __shfl_down(vf, off);
        vs   += __shfl_down(vs, off);
        vn   += __shfl_down(vn, off);
    }
    if (lane == 0) { red[wv][0] = vloc; red[wv][1] = vf; red[wv][2] = vs; redN[wv] = vn; }
    __syncthreads();   // orders sHist atomics before flush + red[] before sum
    if (threadIdx.x == 0) {
        float sl = 0.f, sf = 0.f, ss = 0.f; int sn = 0;
#pragma unroll
        for (int w = 0; w < 4; ++w) { sl += red[w][0]; sf += red[w][1]; ss += red[w][2]; sn += redN[w]; }
        atomicAdd(&accLoc[b], sl);
        atomicAdd(&accFpos[b], sf);
        atomicAdd(&accSiou[b], ss);
        atomicAdd(&accNpos[b], sn);
    }
    int* hb = histC + (size_t)b * NBIN;
    for (int i = threadIdx.x; i < NBIN; i += 256) {
        int c = sHist[i];
        if (c) atomicAdd(&hb[i], c);
    }
}

// ---- kernel 3: top-k sum (hist suffix-scan + one A pass + candidate radix) + final reduce ----
__global__ __launch_bounds__(1024) void kSelectFinal(
    const float* __restrict__ neg, const int* __restrict__ histC,
    const int* __restrict__ accNpos, const float* __restrict__ accFpos,
    const float* __restrict__ accLoc, const float* __restrict__ accSiou,
    float* __restrict__ cand, float* __restrict__ accConf,
    int* __restrict__ counter, float* __restrict__ out, int A)
{
    __shared__ int scanI[1024];
    __shared__ float scanF[1024];
    __shared__ int cnt[1024];
    __shared__ float sm[1024];
    __shared__ float redF[16];
    __shared__ int sh_cb, sh_rem, sh_n, sh_done;
    __shared__ float sh_res, sh_sumHigh;

    int b = blockIdx.x;
    int t = threadIdx.x;
    int npos = accNpos[b];
    int k = min(npos * 3, A - npos);
    bool early = (k <= 0);

    if (!early) {
        int4 c4 = ((const int4*)(histC + (size_t)b * NBIN))[t];
        scanI[t] = c4.x + c4.y + c4.z + c4.w;
        __syncthreads();
        for (int off = 1; off < 1024; off <<= 1) {
            int v = (t + off < 1024) ? scanI[t + off] : 0;
            __syncthreads();
            scanI[t] += v;
            __syncthreads();
        }
        {
            int above = (t + 1 < 1024) ? scanI[t + 1] : 0;
            if (above < k && scanI[t] >= k) {
                int carr[4] = {c4.x, c4.y, c4.z, c4.w};
                int cum = above;
                for (int j = 3; j >= 0; --j) {
                    cum += carr[j];
                    if (cum >= k) { sh_cb = 4 * t + j; sh_rem = k - (cum - carr[j]); break; }
                }
                sh_n = 0; sh_res = 0.f; sh_done = 0;
            }
        }
        __syncthreads();
        int cb = sh_cb;

        float localSum = 0.f;
        const float4* nb4 = (const float4*)(neg + (size_t)b * A);
        float* cb_buf = cand + (size_t)b * A;
        for (int i = t; i < A / 4; i += 1024) {
            float4 v = nb4[i];
            float vv[4] = {v.x, v.y, v.z, v.w};
#pragma unroll
            for (int j = 0; j < 4; ++j) {
                int bin = (int)(__float_as_uint(vv[j]) >> 19);
                if (bin > cb) localSum += vv[j];
                else if (bin == cb) {
                    int idx = atomicAdd(&sh_n, 1);
                    cb_buf[idx] = vv[j];
                }
            }
        }
        {
            int lane = t & 63, wv = t >> 6;
            for (int off = 32; off > 0; off >>= 1) localSum += __shfl_down(localSum, off);
            if (lane == 0) redF[wv] = localSum;
        }
        __syncthreads();
        if (t == 0) {
            float tot = 0.f;
            for (int w = 0; w < 16; ++w) tot += redF[w];
            sh_sumHigh = tot;
        }
        __syncthreads();
        int n = sh_n;
        int rem = sh_rem;

        cnt[t] = 0; sm[t] = 0.f;
        __syncthreads();
        for (int i = t; i < n; i += 1024) {
            float v = cb_buf[i];
            int bin = (int)((__float_as_uint(v) >> 9) & 1023u);
            atomicAdd(&cnt[bin], 1);
            atomicAdd(&sm[bin], v);
        }
        __syncthreads();
        scanI[t] = cnt[t]; scanF[t] = sm[t];
        __syncthreads();
        for (int off = 1; off < 1024; off <<= 1) {
            int vi = 0; float vf = 0.f;
            if (t + off < 1024) { vi = scanI[t + off]; vf = scanF[t + off]; }
            __syncthreads();
            scanI[t] += vi; scanF[t] += vf;
            __syncthreads();
        }
        {
            int aboveC = (t + 1 < 1024) ? scanI[t + 1] : 0;
            if (aboveC < rem && scanI[t] >= rem) {
                float aboveS = (t + 1 < 1024) ? scanF[t + 1] : 0.f;
                int need = rem - aboveC;
                if (cnt[t] == need) { sh_res += aboveS + sm[t]; sh_done = 1; }
                else { sh_res += aboveS; sh_rem = need; sh_cb = t; }
            }
        }
        __syncthreads();
        if (!sh_done) {
            int cb2 = sh_cb;
            rem = sh_rem;
            if (t < 512) { cnt[t] = 0; sm[t] = 0.f; }
            __syncthreads();
            for (int i = t; i < n; i += 1024) {
                float v = cb_buf[i];
                unsigned int u = __float_as_uint(v);
                if ((int)((u >> 9) & 1023u) == cb2) {
                    int bin = (int)(u & 511u);
                    atomicAdd(&cnt[bin], 1);
                    atomicAdd(&sm[bin], v);
                }
            }
            __syncthreads();
            scanI[t] = (t < 512) ? cnt[t] : 0;
            scanF[t] = (t < 512) ? sm[t] : 0.f;
            __syncthreads();
            for (int off = 1; off < 512; off <<= 1) {
                int vi = 0; float vf = 0.f;
                if (t + off < 512) { vi = scanI[t + off]; vf = scanF[t + off]; }
                __syncthreads();
                if (t < 512) { scanI[t] += vi; scanF[t] += vf; }
                __syncthreads();
            }
            if (t < 512) {
                int aboveC = (t + 1 < 512) ? scanI[t + 1] : 0;
                if (aboveC < rem && scanI[t] >= rem) {
                    float aboveS = (t + 1 < 512) ? scanF[t + 1] : 0.f;
                    int need = rem - aboveC;
                    if (cnt[t] == need) {
                        sh_res += aboveS + sm[t];
                    } else {
                        unsigned int u = ((unsigned int)cb << 19) | ((unsigned int)cb2 << 9) | (unsigned int)t;
                        sh_res += aboveS + (float)need * __uint_as_float(u);
                    }
                }
            }
            __syncthreads();
        }
    }

    if (t == 0) {
        accConf[b] = early ? accFpos[b] : (sh_sumHigh + sh_res + accFpos[b]);
        __threadfence();
        int nB = (int)gridDim.x;
        if (atomicAdd(counter, 1) == nB - 1) {   // last block does the final reduce
            __threadfence();
            float loc = 0.f, cf = 0.f, si = 0.f; int np = 0;
            for (int i = 0; i < nB; ++i) {
                loc += accLoc[i]; cf += accConf[i]; si += accSiou[i]; np += accNpos[i];
            }
            float denom = fmaxf(1.f, (float)np);
            float tl = loc / denom, tc = cf / denom;
            out[0] = tl + tc;
            out[1] = tc;
            out[2] = tl;
            out[3] = si / denom;
        }
    }
}

extern "C" void kernel_launch(void* const* d_in, const int* in_sizes, int n_in,
                              void* d_out, int out_size, void* d_ws, size_t ws_size,
                              hipStream_t stream)
{
    const float4* bbox    = (const float4*)d_in[0];
    const float*  conf    = (const float*)d_in[1];
    const float4* anchors = (const float4*)d_in[2];
    const float4* gt      = (const float4*)d_in[3];
    int A = in_sizes[2] / 4;
    int B = in_sizes[1] / A;
    int G = in_sizes[3] / (4 * B);
    float* out = (float*)d_out;

    char* ws = (char*)d_ws;
    size_t off = 0;
    float* neg  = (float*)(ws + off); off += (size_t)B * A * sizeof(float);
    float* cand = (float*)(ws + off); off += (size_t)B * A * sizeof(float);
    unsigned long long* wsKeyPart = (unsigned long long*)(ws + off);
    off += (size_t)B * G * ASPLIT * sizeof(unsigned long long);
    int* histC = (int*)(ws + off); off += (size_t)B * NBIN * sizeof(int);
    char* accBase = ws + off;                       // 16B-aligned; zeroed by kBestAnchor block 0
    float* accLoc  = (float*)(accBase + 0);
    float* accFpos = (float*)(accBase + 64);
    float* accSiou = (float*)(accBase + 128);
    float* accConf = (float*)(accBase + 192);
    int*   accNpos = (int*)(accBase + 256);
    int*   counter = (int*)(accBase + 320);
    // acc block = 512 bytes (32 uint4), zeroed in-kernel each call (replay-safe)

    int nch = G / GPER;
    kBestAnchor<<<dim3(B * nch * ASPLIT), 256, 0, stream>>>(
        anchors, gt, wsKeyPart, (uint4*)histC, (uint4*)accBase, A, G);
    kMain<<<dim3(A / 512, B), 256, 0, stream>>>(
        bbox, conf, anchors, gt, wsKeyPart,
        neg, histC, accLoc, accFpos, accSiou, accNpos, A, G);
    kSelectFinal<<<dim3(B), 1024, 0, stream>>>(
        neg, histC, accNpos, accFpos, accLoc, accSiou, cand, accConf, counter, out, A);
}

// Round 9
// 70.943 us; speedup vs baseline: 1.4527x; 1.0384x over previous
//
#include <hip/hip_runtime.h>
#include <math.h>

#define IOU_TH 0.5f
#define EPSF 1e-6f
#define GPER 8
#define ASPLIT 16
#define NBIN 4096

__device__ __forceinline__ float sl1(float x) {
    float ax = fabsf(x);
    return ax < 1.f ? 0.5f * x * x : ax - 0.5f;
}

__device__ __forceinline__ unsigned long long umax64(unsigned long long a, unsigned long long b) {
    return a > b ? a : b;
}

// ---- kernel 1: best anchor per (b,g,part) -> plain store; side duty: zero histC + acc ----
__global__ __launch_bounds__(256) void kBestAnchor(
    const float4* __restrict__ anchors, const float4* __restrict__ gt,
    unsigned long long* __restrict__ wsKeyPart,
    uint4* __restrict__ histZero, uint4* __restrict__ accZero,
    int A, int G)
{
    // zero duty: 2048 blocks x 8 uint4 = histC (256KB); block 0 also zeroes acc block (512B)
    if (threadIdx.x < 8) histZero[blockIdx.x * 8 + threadIdx.x] = make_uint4(0u, 0u, 0u, 0u);
    if (blockIdx.x == 0 && threadIdx.x >= 64 && threadIdx.x < 96)
        accZero[threadIdx.x - 64] = make_uint4(0u, 0u, 0u, 0u);

    int nch = G / GPER;
    int b   = blockIdx.x / (nch * ASPLIT);
    int r   = blockIdx.x % (nch * ASPLIT);
    int g0  = (r / ASPLIT) * GPER;
    int part = r % ASPLIT;
    int aChunk = A / ASPLIT;
    int a0  = part * aChunk;

    float4 gb[GPER]; float ga[GPER];
#pragma unroll
    for (int j = 0; j < GPER; ++j) {
        gb[j] = gt[(size_t)b * G + g0 + j];
        ga[j] = (gb[j].z - gb[j].x) * (gb[j].w - gb[j].y);
    }
    float bi[GPER], bd[GPER]; int bx[GPER];
#pragma unroll
    for (int j = 0; j < GPER; ++j) { bi[j] = -1.f; bd[j] = 1.f; bx[j] = a0; }
    for (int a = a0 + threadIdx.x; a < a0 + aChunk; a += 256) {
        float4 ab = anchors[a];
        float aa = (ab.z - ab.x) * (ab.w - ab.y);
#pragma unroll
        for (int j = 0; j < GPER; ++j) {
            float wx = fmaxf(fminf(ab.z, gb[j].z) - fmaxf(ab.x, gb[j].x), 0.f);
            float wy = fmaxf(fminf(ab.w, gb[j].w) - fmaxf(ab.y, gb[j].y), 0.f);
            float inter = wx * wy;
            float den = aa + ga[j] - inter + EPSF;
            if (inter * bd[j] > bi[j] * den) { bi[j] = inter; bd[j] = den; bx[j] = a; }
        }
    }
    int lane = threadIdx.x & 63, wv = threadIdx.x >> 6;
    __shared__ float ri[4][GPER], rd[4][GPER]; __shared__ int rx[4][GPER];
#pragma unroll
    for (int j = 0; j < GPER; ++j) {
        float ci = bi[j], cd = bd[j]; int cx = bx[j];
        for (int off = 32; off > 0; off >>= 1) {
            float oi = __shfl_down(ci, off);
            float od = __shfl_down(cd, off);
            int   ox = __shfl_down(cx, off);
            if (lane + off < 64) {
                float lp = oi * cd, rp = ci * od;
                if (lp > rp || (lp == rp && ox < cx)) { ci = oi; cd = od; cx = ox; }
            }
        }
        if (lane == 0) { ri[wv][j] = ci; rd[wv][j] = cd; rx[wv][j] = cx; }
    }
    __syncthreads();
    if (threadIdx.x < GPER) {
        int j = threadIdx.x;
        float ci = ri[0][j], cd = rd[0][j]; int cx = rx[0][j];
        for (int w = 1; w < 4; ++w) {
            float oi = ri[w][j], od = rd[w][j]; int ox = rx[w][j];
            float lp = oi * cd, rp = ci * od;
            if (lp > rp || (lp == rp && ox < cx)) { ci = oi; cd = od; cx = ox; }
        }
        float iou = ci / cd;   // divided value compared across parts (matches jnp semantics)
        unsigned long long key =
            ((unsigned long long)__float_as_uint(iou) << 32) | (unsigned int)(~(unsigned int)cx);
        wsKeyPart[((size_t)b * G + g0 + j) * ASPLIT + part] = key;   // plain store, no init needed
    }
}

// ------- kernel 2: per-anchor match + losses, 4 anchors/thread, in-kernel winner decode ----
__global__ __launch_bounds__(256) void kMain(
    const float4* __restrict__ bbox, const float* __restrict__ conf,
    const float4* __restrict__ anchors, const float4* __restrict__ gt,
    const unsigned long long* __restrict__ wsKeyPart,
    float* __restrict__ neg, int* __restrict__ histC,
    float* __restrict__ accLoc, float* __restrict__ accFpos,
    float* __restrict__ accSiou, int* __restrict__ accNpos,
    int A, int G)
{
    __shared__ float4 sGt[64];
    __shared__ float sGa[64];
    __shared__ int sHist[NBIN];
    __shared__ unsigned long long sKeyQ[256];
    __shared__ unsigned char sPosFlag[1024];
    __shared__ float red[4][3]; __shared__ int redN[4];
    int b = blockIdx.y;
    for (int i = threadIdx.x; i < NBIN; i += 256) sHist[i] = 0;
#pragma unroll
    for (int k = 0; k < 4; ++k) sPosFlag[threadIdx.x + k * 256] = 0;
    if (threadIdx.x < G) {
        float4 g = gt[(size_t)b * G + threadIdx.x];
        sGt[threadIdx.x] = g;
        sGa[threadIdx.x] = (g.z - g.x) * (g.w - g.y);
    }
    // winner decode stage 1: thread t covers gt (t>>2), parts 4*(t&3)..+3
    {
        int g = threadIdx.x >> 2, p0 = (threadIdx.x & 3) * 4;
        const unsigned long long* kp = wsKeyPart + ((size_t)b * G + g) * ASPLIT + p0;
        unsigned long long m = umax64(umax64(kp[0], kp[1]), umax64(kp[2], kp[3]));
        sKeyQ[threadIdx.x] = m;
    }

    int aBase = blockIdx.x * 1024 + threadIdx.x;   // A % 1024 == 0
    float4 an[4], p4[4]; float cp[4]; float aa[4];
#pragma unroll
    for (int k = 0; k < 4; ++k) {
        int a = aBase + k * 256;
        an[k] = anchors[a];
        p4[k] = bbox[(size_t)b * A + a];
        cp[k] = conf[(size_t)b * A + a];
        aa[k] = (an[k].z - an[k].x) * (an[k].w - an[k].y);
    }
    __syncthreads();   // sKeyQ + sGt/sGa + zeroed flags visible
    // winner decode stage 2: t<64 reduces 4 quads, flags winners inside this block's range
    if (threadIdx.x < 64) {
        int t4 = threadIdx.x * 4;
        unsigned long long m = umax64(umax64(sKeyQ[t4], sKeyQ[t4 + 1]),
                                      umax64(sKeyQ[t4 + 2], sKeyQ[t4 + 3]));
        unsigned int idx = ~(unsigned int)(m & 0xFFFFFFFFull);
        unsigned int local = idx - (unsigned int)(blockIdx.x * 1024);
        if (local < 1024u) sPosFlag[local] = 1;
    }
    __syncthreads();   // flags ready

    // argmax over g: 4 chains per anchor x 4 anchors = 16 independent chains
    float bi[4][4], bd[4][4]; int bx[4][4];
#pragma unroll
    for (int k = 0; k < 4; ++k)
#pragma unroll
        for (int c = 0; c < 4; ++c) { bi[k][c] = -1.f; bd[k][c] = 1.f; bx[k][c] = c; }
#pragma unroll 2
    for (int g = 0; g < G; g += 4) {
        float4 q0 = sGt[g], q1 = sGt[g + 1], q2 = sGt[g + 2], q3 = sGt[g + 3];
        float4 ga4 = *(const float4*)&sGa[g];
        float qz[4] = {q0.z, q1.z, q2.z, q3.z};
        float qx[4] = {q0.x, q1.x, q2.x, q3.x};
        float qw[4] = {q0.w, q1.w, q2.w, q3.w};
        float qy[4] = {q0.y, q1.y, q2.y, q3.y};
        float gv[4] = {ga4.x, ga4.y, ga4.z, ga4.w};
#pragma unroll
        for (int j = 0; j < 4; ++j) {
#pragma unroll
            for (int k = 0; k < 4; ++k) {
                float wx = fmaxf(fminf(an[k].z, qz[j]) - fmaxf(an[k].x, qx[j]), 0.f);
                float wy = fmaxf(fminf(an[k].w, qw[j]) - fmaxf(an[k].y, qy[j]), 0.f);
                float inter = wx * wy;
                float den = aa[k] + gv[j] - inter + EPSF;
                if (inter * bd[k][j] > bi[k][j] * den) {
                    bi[k][j] = inter; bd[k][j] = den; bx[k][j] = g + j;
                }
            }
        }
    }

    float vloc = 0.f, vf = 0.f, vs = 0.f; int vn = 0;
    bool pos[4]; int Bx[4];
    bool anyP = false;
#pragma unroll
    for (int k = 0; k < 4; ++k) {
        float ci = bi[k][0], cd = bd[k][0]; int cx = bx[k][0];
#pragma unroll
        for (int c = 1; c < 4; ++c) {
            float lp = bi[k][c] * cd, rp = ci * bd[k][c];
            if (lp > rp || (lp == rp && bx[k][c] < cx)) { ci = bi[k][c]; cd = bd[k][c]; cx = bx[k][c]; }
        }
        Bx[k] = cx;
        pos[k] = (ci / cd > IOU_TH) || (sPosFlag[threadIdx.x + k * 256] != 0);
        anyP |= pos[k];
    }
    bool anyPos = __any(anyP);
#pragma unroll
    for (int k = 0; k < 4; ++k) {
        float box_loss = 0.f, a_iou = 0.f;
        if (anyPos) {   // wave-uniform: all-negative waves (~95%) skip
            float4 m = sGt[Bx[k]];
            float pa = (p4[k].z - p4[k].x) * (p4[k].w - p4[k].y);
            float ta = (m.z - m.x) * (m.w - m.y);
            float wx = fmaxf(fminf(p4[k].z, m.z) - fmaxf(p4[k].x, m.x), 0.f);
            float wy = fmaxf(fminf(p4[k].w, m.w) - fmaxf(p4[k].y, m.y), 0.f);
            float inter = wx * wy;
            a_iou = inter / (pa + ta - inter + EPSF);
            float ex = fmaxf(fmaxf(p4[k].z, m.z) - fminf(p4[k].x, m.x), 0.f);
            float ey = fmaxf(fmaxf(p4[k].w, m.w) - fminf(p4[k].y, m.y), 0.f);
            float enc = ex * ey + EPSF;
            float uni = pa + ta - a_iou * pa * ta;
            float gl = 1.f - (a_iou - (enc - uni) / enc);
            float cl = sl1((p4[k].x + p4[k].z) * 0.5f - (m.x + m.z) * 0.5f)
                     + sl1((p4[k].y + p4[k].w) * 0.5f - (m.y + m.w) * 0.5f);
            float szl = sl1((p4[k].z - p4[k].x) - (m.z - m.x))
                      + sl1((p4[k].w - p4[k].y) - (m.w - m.y));
            box_loss = 0.5f * (cl + szl) + 0.5f * gl;
        }
        float t = pos[k] ? a_iou : 0.f;
        float pcl = fminf(fmaxf(cp[k], 1e-7f), 1.f - 1e-7f);
        float bce;
        if (anyPos) bce = -(t * logf(pcl) + (1.f - t) * log1pf(-pcl));
        else        bce = -log1pf(-pcl);        // t == 0 exactly
        float pt = (t > 0.f) ? cp[k] : (1.f - cp[k]);
        float om = 1.f - pt;
        float f = om * om * ((t > 0.f) ? 0.25f : 0.75f) * bce;

        neg[(size_t)b * A + aBase + k * 256] = pos[k] ? 0.f : f;
        if (!pos[k]) {
            unsigned int u = __float_as_uint(f);
            atomicAdd(&sHist[u >> 19], 1);
        }
        vloc += pos[k] ? box_loss : 0.f;
        vf   += pos[k] ? f : 0.f;
        vs   += pos[k] ? a_iou : 0.f;
        vn   += pos[k] ? 1 : 0;
    }

    int lane = threadIdx.x & 63, wv = threadIdx.x >> 6;
    for (int off = 32; off > 0; off >>= 1) {
        vloc += __shfl_down(vloc, off);
        vf   += __shfl_down(vf, off);
        vs   += __shfl_down(vs, off);
        vn   += __shfl_down(vn, off);
    }
    if (lane == 0) { red[wv][0] = vloc; red[wv][1] = vf; red[wv][2] = vs; redN[wv] = vn; }
    __syncthreads();   // orders sHist atomics before flush + red[] before sum
    if (threadIdx.x == 0) {
        float sl = 0.f, sf = 0.f, ss = 0.f; int sn = 0;
#pragma unroll
        for (int w = 0; w < 4; ++w) { sl += red[w][0]; sf += red[w][1]; ss += red[w][2]; sn += redN[w]; }
        atomicAdd(&accLoc[b], sl);
        atomicAdd(&accFpos[b], sf);
        atomicAdd(&accSiou[b], ss);
        atomicAdd(&accNpos[b], sn);
    }
    int* hb = histC + (size_t)b * NBIN;
    for (int i = threadIdx.x; i < NBIN; i += 256) {
        int c = sHist[i];
        if (c) atomicAdd(&hb[i], c);
    }
}

// ---- kernel 3: top-k sum via wave-shuffle suffix scans + final reduce (ticketed) ----
__global__ __launch_bounds__(1024) void kSelectFinal(
    const float* __restrict__ neg, const int* __restrict__ histC,
    const int* __restrict__ accNpos, const float* __restrict__ accFpos,
    const float* __restrict__ accLoc, const float* __restrict__ accSiou,
    float* __restrict__ cand, float* __restrict__ accConf,
    int* __restrict__ counter, float* __restrict__ out, int A)
{
    __shared__ int cnt[1024];
    __shared__ float sm[1024];
    __shared__ int shI[16];
    __shared__ float shF[16];
    __shared__ float redF[16];
    __shared__ int sh_cb, sh_rem, sh_n, sh_done;
    __shared__ float sh_res, sh_sumHigh;

    int b = blockIdx.x;
    int t = threadIdx.x;
    int lane = t & 63, wv = t >> 6;
    int npos = accNpos[b];
    int k = min(npos * 3, A - npos);
    bool early = (k <= 0);

    if (!early) {
        // ---- level 0: cutoff bin via wave-shuffle suffix scan of 4096-bin hist ----
        int4 c4 = ((const int4*)(histC + (size_t)b * NBIN))[t];
        int v0 = c4.x + c4.y + c4.z + c4.w;
        int ci = v0;
        for (int off = 1; off < 64; off <<= 1) {
            int oi = __shfl_down(ci, off);
            if (lane + off < 64) ci += oi;
        }
        if (lane == 0) shI[wv] = ci;           // wave total
        __syncthreads();
        int addI = 0;
        for (int w = wv + 1; w < 16; ++w) addI += shI[w];
        int si = ci + addI;                     // inclusive suffix over all 1024 threads
        int above = si - v0;                    // strictly-above suffix
        if (above < k && si >= k) {             // crossing inside my 4 bins (unique thread)
            int carr[4] = {c4.x, c4.y, c4.z, c4.w};
            int cum = above;
            for (int j = 3; j >= 0; --j) {
                cum += carr[j];
                if (cum >= k) { sh_cb = 4 * t + j; sh_rem = k - (cum - carr[j]); break; }
            }
            sh_n = 0; sh_res = 0.f; sh_done = 0;
        }
        __syncthreads();
        int cb = sh_cb;

        // ---- one pass over A: sum bins>cb, gather bin==cb candidates ----
        float localSum = 0.f;
        const float4* nb4 = (const float4*)(neg + (size_t)b * A);
        float* cb_buf = cand + (size_t)b * A;
        for (int i = t; i < A / 4; i += 1024) {
            float4 v = nb4[i];
            float vv[4] = {v.x, v.y, v.z, v.w};
#pragma unroll
            for (int j = 0; j < 4; ++j) {
                int bin = (int)(__float_as_uint(vv[j]) >> 19);
                if (bin > cb) localSum += vv[j];
                else if (bin == cb) {
                    int idx = atomicAdd(&sh_n, 1);
                    cb_buf[idx] = vv[j];
                }
            }
        }
        for (int off = 32; off > 0; off >>= 1) localSum += __shfl_down(localSum, off);
        if (lane == 0) redF[wv] = localSum;
        __syncthreads();
        if (t == 0) {
            float tot = 0.f;
            for (int w = 0; w < 16; ++w) tot += redF[w];
            sh_sumHigh = tot;
        }
        int n_snapshot = sh_n;   // read after barrier above? guard with another barrier below
        __syncthreads();
        int n = sh_n;
        int rem = sh_rem;
        (void)n_snapshot;

        // ---- level 1: bits 18..9 of candidates ----
        cnt[t] = 0; sm[t] = 0.f;
        __syncthreads();
        for (int i = t; i < n; i += 1024) {
            float v = cb_buf[i];
            int bin = (int)((__float_as_uint(v) >> 9) & 1023u);
            atomicAdd(&cnt[bin], 1);
            atomicAdd(&sm[bin], v);
        }
        __syncthreads();
        int v1 = cnt[t]; float f1 = sm[t];
        {
            int ci1 = v1; float cf1 = f1;
            for (int off = 1; off < 64; off <<= 1) {
                int oi = __shfl_down(ci1, off);
                float of = __shfl_down(cf1, off);
                if (lane + off < 64) { ci1 += oi; cf1 += of; }
            }
            if (lane == 0) { shI[wv] = ci1; shF[wv] = cf1; }
            __syncthreads();
            int aI = 0; float aF = 0.f;
            for (int w = wv + 1; w < 16; ++w) { aI += shI[w]; aF += shF[w]; }
            int s1 = ci1 + aI; float sf1 = cf1 + aF;
            int aboveC = s1 - v1; float aboveS = sf1 - f1;
            if (aboveC < rem && s1 >= rem) {
                int need = rem - aboveC;
                if (v1 == need) { sh_res += aboveS + f1; sh_done = 1; }
                else { sh_res += aboveS; sh_rem = need; sh_cb = t; }
            }
        }
        __syncthreads();
        if (!sh_done) {
            int cb2 = sh_cb;
            rem = sh_rem;
            // ---- level 2: bits 8..0, filtered on level-1 bin ----
            if (t < 512) { cnt[t] = 0; sm[t] = 0.f; }
            __syncthreads();
            for (int i = t; i < n; i += 1024) {
                float v = cb_buf[i];
                unsigned int u = __float_as_uint(v);
                if ((int)((u >> 9) & 1023u) == cb2) {
                    int bin = (int)(u & 511u);
                    atomicAdd(&cnt[bin], 1);
                    atomicAdd(&sm[bin], v);
                }
            }
            __syncthreads();
            int v2 = (t < 512) ? cnt[t] : 0;
            float f2 = (t < 512) ? sm[t] : 0.f;
            int ci2 = v2; float cf2 = f2;
            for (int off = 1; off < 64; off <<= 1) {
                int oi = __shfl_down(ci2, off);
                float of = __shfl_down(cf2, off);
                if (lane + off < 64) { ci2 += oi; cf2 += of; }
            }
            if (lane == 0) { shI[wv] = ci2; shF[wv] = cf2; }
            __syncthreads();
            int aI = 0; float aF = 0.f;
            for (int w = wv + 1; w < 16; ++w) { aI += shI[w]; aF += shF[w]; }
            int s2 = ci2 + aI; float sf2 = cf2 + aF;
            int aboveC = s2 - v2; float aboveS = sf2 - f2;
            if (aboveC < rem && s2 >= rem) {   // only t<512 can trigger (v2==0 above)
                int need = rem - aboveC;
                if (v2 == need) {
                    sh_res += aboveS + f2;
                } else {
                    // all 32 bits identical in this bin -> exact value
                    unsigned int u = ((unsigned int)cb << 19) | ((unsigned int)cb2 << 9) | (unsigned int)t;
                    sh_res += aboveS + (float)need * __uint_as_float(u);
                }
            }
            __syncthreads();
        }
    }

    if (t == 0) {
        accConf[b] = early ? accFpos[b] : (sh_sumHigh + sh_res + accFpos[b]);
        __threadfence();
        int nB = (int)gridDim.x;
        if (atomicAdd(counter, 1) == nB - 1) {   // last block does the final reduce
            __threadfence();
            float loc = 0.f, cf = 0.f, si = 0.f; int np = 0;
            for (int i = 0; i < nB; ++i) {
                loc += accLoc[i]; cf += accConf[i]; si += accSiou[i]; np += accNpos[i];
            }
            float denom = fmaxf(1.f, (float)np);
            float tl = loc / denom, tc = cf / denom;
            out[0] = tl + tc;
            out[1] = tc;
            out[2] = tl;
            out[3] = si / denom;
        }
    }
}

extern "C" void kernel_launch(void* const* d_in, const int* in_sizes, int n_in,
                              void* d_out, int out_size, void* d_ws, size_t ws_size,
                              hipStream_t stream)
{
    const float4* bbox    = (const float4*)d_in[0];
    const float*  conf    = (const float*)d_in[1];
    const float4* anchors = (const float4*)d_in[2];
    const float4* gt      = (const float4*)d_in[3];
    int A = in_sizes[2] / 4;
    int B = in_sizes[1] / A;
    int G = in_sizes[3] / (4 * B);
    float* out = (float*)d_out;

    char* ws = (char*)d_ws;
    size_t off = 0;
    float* neg  = (float*)(ws + off); off += (size_t)B * A * sizeof(float);
    float* cand = (float*)(ws + off); off += (size_t)B * A * sizeof(float);
    unsigned long long* wsKeyPart = (unsigned long long*)(ws + off);
    off += (size_t)B * G * ASPLIT * sizeof(unsigned long long);
    int* histC = (int*)(ws + off); off += (size_t)B * NBIN * sizeof(int);
    char* accBase = ws + off;                       // 16B-aligned; zeroed by kBestAnchor block 0
    float* accLoc  = (float*)(accBase + 0);
    float* accFpos = (float*)(accBase + 64);
    float* accSiou = (float*)(accBase + 128);
    float* accConf = (float*)(accBase + 192);
    int*   accNpos = (int*)(accBase + 256);
    int*   counter = (int*)(accBase + 320);
    // acc block = 512 bytes (32 uint4), zeroed in-kernel each call (replay-safe)

    int nch = G / GPER;
    kBestAnchor<<<dim3(B * nch * ASPLIT), 256, 0, stream>>>(
        anchors, gt, wsKeyPart, (uint4*)histC, (uint4*)accBase, A, G);
    kMain<<<dim3(A / 1024, B), 256, 0, stream>>>(
        bbox, conf, anchors, gt, wsKeyPart,
        neg, histC, accLoc, accFpos, accSiou, accNpos, A, G);
    kSelectFinal<<<dim3(B), 1024, 0, stream>>>(
        neg, histC, accNpos, accFpos, accLoc, accSiou, cand, accConf, counter, out, A);
}